// Round 11
// baseline (203.168 us; speedup 1.0000x reference)
//
#include <hip/hip_runtime.h>

// Problem constants
#define BB 128
#define TT 6
#define KK 64
#define DD 8
#define HH 128
#define NSTEP 5
#define LDP 136      // padded LDS row (u16 elems): 272B = 17*16B, 16B-aligned rows
#define PREDSZ (BB*NSTEP*KK*DD)   // 327680

typedef unsigned short u16;
typedef unsigned int   u32;
typedef _Float16 f16;
typedef __attribute__((ext_vector_type(8))) _Float16 f16x8;
typedef __attribute__((ext_vector_type(4))) float f32x4;
typedef __attribute__((ext_vector_type(2))) _Float16 h2;

union h2u { u32 u; h2 h; };
union hu  { u16 u; f16 h; };

__device__ __forceinline__ u16 f2h_bits(float f){
  hu v; v.h = (f16)f; return v.u;     // v_cvt_f16_f32, 1 instr
}
__device__ __forceinline__ u32 pk2(float x, float y){  // two cvts + pack
  hu a, b; a.h = (f16)x; b.h = (f16)y;
  return (u32)a.u | ((u32)b.u << 16);
}
__device__ __forceinline__ h2 u2h(u32 x){ h2u t; t.u = x; return t.h; }
__device__ __forceinline__ u32 h2u_(h2 x){ h2u t; t.h = x; return t.u; }

// ---------------- ws layout (u16 element offsets) ----------------
// Fused weight matrices (exact fp32 products, cast f16), wave-coalesced frags:
//   FR[g=8][kc=4][lane=64][8] : elem off = g*2048 + kc*512 + lane*8
// SUIU (K=256): FR[g=8][kc=8][lane=64][8], kc<4 = SU rows, kc>=4 = IU rows.
#define O_EWA   0        // ew2 @ wi_a
#define O_EWB   16384    // ew2 @ wi_b
#define O_EWS   32768    // ew2 @ self_w1
#define O_SUIU  49152    // [self_w2 @ uw1_top | (inter_w2 @ uw1_bot)/64]  (32768 elems)
#define O_UD    81920    // upd_w2 @ dec_w1
#define O_DET   98304    // dec_w2 @ enc_w1
#define O_DW2T  114688   // dw2 transposed f16 [8][128]
#define BIASF   57856    // float idx: bA,bB,bS,bU,bUD,deb  (6 x 128 f32)
// pair-exchange region:
#define O_XBUF  131072                    // u16: [pairslot=batch*2+half][slot=2][4096]
#define O_FLAG  (O_XBUF + 128*2*2*4096)   // u16 offset of u32 flags[256][2]

// ---- 16-row GEMM: O(16 local rows x 128) = A@W [+ bias]; wave (wn,wm) -> 16 cols, 1 m-tile ----
// A, O are 32-row local buffers; rows (wm<<4)+...
template<bool RELU>
__device__ __forceinline__ void gemm16(const u16 (*A)[LDP], const u16* __restrict__ wt,
    float bias, u16 (*O)[LDP], int wn, int wm, int l15, int q, int n, int lane)
{
  f16x8 bf[4];
#pragma unroll
  for (int kc=0; kc<4; ++kc)
    bf[kc] = *(const f16x8*)(wt + (wn<<11) + (kc<<9) + (lane<<3));
  f32x4 acc = {0.f,0.f,0.f,0.f};
#pragma unroll
  for (int kc=0; kc<4; ++kc){
    f16x8 af = *(const f16x8*)&A[(wm<<4)+l15][(kc<<5)+(q<<3)];
    acc = __builtin_amdgcn_mfma_f32_16x16x32_f16(af, bf[kc], acc, 0,0,0);
  }
#pragma unroll
  for (int e=0; e<4; ++e){
    float v = acc[e] + bias;
    if (RELU) v = fmaxf(v, 0.f);
    O[(wm<<4)+(q<<2)+e][n] = f2h_bits(v);   // C/D: col=lane&15, row=q*4+e
  }
}

// K=256: O(16 local rows) = relu([A1 | A2] @ [SU|IU] + bU); A1/A2 32-row local buffers
__device__ __forceinline__ void gemm256_16(const u16 (*A1)[LDP], const u16 (*A2)[LDP],
    const u16* __restrict__ wt, float bias, u16 (*O)[LDP], int wn, int wm, int l15, int q, int n, int lane)
{
  f16x8 bf[8];
#pragma unroll
  for (int kc=0; kc<8; ++kc)
    bf[kc] = *(const f16x8*)(wt + (wn<<12) + (kc<<9) + (lane<<3));
  f32x4 acc = {0.f,0.f,0.f,0.f};
#pragma unroll
  for (int kc=0; kc<8; ++kc){
    const u16 (*As)[LDP] = (kc<4) ? A1 : A2;
    f16x8 af = *(const f16x8*)&As[(wm<<4)+l15][((kc&3)<<5)+(q<<3)];
    acc = __builtin_amdgcn_mfma_f32_16x16x32_f16(af, bf[kc], acc, 0,0,0);
  }
#pragma unroll
  for (int e=0; e<4; ++e){
    float v = fmaxf(acc[e] + bias, 0.f);
    O[(wm<<4)+(q<<2)+e][n] = f2h_bits(v);
  }
}

// ---- Fused stage1 + interaction, 16-wave pair-split version ----
// Block (batch,half) holds FULL h (64 rows) in P. Wave (wn,wm) computes:
//   a = h@EWA for ALL 64 rows x its 16 cols (full height required by sum over i);
//   b, hs only for its own 16 rows (global rows rowbase = half*32 + wm*16);
//   interaction Ssum[j,n] = sum_i relu(a[i,n]+b[j,n]) for its own 16 j's, wave-locally.
__device__ __forceinline__ void fusedS1I(const u16 (*P)[LDP], const u16* __restrict__ ws,
    float bAv, float bBv, float bSv,
    u16 (*Q)[LDP], u16 (*S)[LDP],
    int wn, int wm, int half, int l15, int q, int n, int lane)
{
  const int rowbase = (half<<5) + (wm<<4);
  u32 aPk[4][2];   // [mt][pair]: a rows mt*16+q*4+{2p,2p+1}, col n (f16 pairs)
  {
    f16x8 fa[4];
#pragma unroll
    for (int kc=0; kc<4; ++kc)
      fa[kc] = *(const f16x8*)(ws + O_EWA + (wn<<11) + (kc<<9) + (lane<<3));
#pragma unroll
    for (int mt=0; mt<4; ++mt){
      f32x4 aA = {0.f,0.f,0.f,0.f};
#pragma unroll
      for (int kc=0; kc<4; ++kc){
        f16x8 af = *(const f16x8*)&P[(mt<<4)+l15][(kc<<5)+(q<<3)];
        aA = __builtin_amdgcn_mfma_f32_16x16x32_f16(af, fa[kc], aA, 0,0,0);
      }
      aPk[mt][0] = pk2(aA[0]+bAv, aA[1]+bAv);
      aPk[mt][1] = pk2(aA[2]+bAv, aA[3]+bAv);
    }
  }
  u32 bPk[2];
  {
    f16x8 fb[4], fs[4], af[4];
#pragma unroll
    for (int kc=0; kc<4; ++kc){
      const int o = (wn<<11) + (kc<<9) + (lane<<3);
      fb[kc] = *(const f16x8*)(ws + O_EWB + o);
      fs[kc] = *(const f16x8*)(ws + O_EWS + o);
      af[kc] = *(const f16x8*)&P[rowbase+l15][(kc<<5)+(q<<3)];
    }
    f32x4 aB = {0.f,0.f,0.f,0.f}, aS = {0.f,0.f,0.f,0.f};
#pragma unroll
    for (int kc=0; kc<4; ++kc){
      aB = __builtin_amdgcn_mfma_f32_16x16x32_f16(af[kc], fb[kc], aB, 0,0,0);
      aS = __builtin_amdgcn_mfma_f32_16x16x32_f16(af[kc], fs[kc], aS, 0,0,0);
    }
    bPk[0] = pk2(aB[0]+bBv, aB[1]+bBv);
    bPk[1] = pk2(aB[2]+bBv, aB[3]+bBv);
#pragma unroll
    for (int e=0; e<4; ++e)
      S[(wm<<4)+(q<<2)+e][n] = f2h_bits(fmaxf(aS[e]+bSv, 0.f));
  }

  // gather the 16 own b's across q-lanes
  u32 jt[4][2];
#pragma unroll
  for (int qp=0; qp<4; ++qp){
    const int src = (qp<<4) + l15;
    jt[qp][0] = (u32)__shfl((int)bPk[0], src);
    jt[qp][1] = (u32)__shfl((int)bPk[1], src);
  }
  h2 z; z.x = (f16)0.f; z.y = (f16)0.f;
  h2 s[4][2];
#pragma unroll
  for (int qp=0; qp<4; ++qp){ s[qp][0] = z; s[qp][1] = z; }
  // accumulate over this thread's 16 i-values (4 mt x 2 pairs x 2 f16)
#pragma unroll
  for (int mt=0; mt<4; ++mt)
#pragma unroll
    for (int pp=0; pp<2; ++pp){
      const u32 ap = aPk[mt][pp];
      const h2 hl = u2h(__builtin_amdgcn_perm(ap, ap, 0x01000100));  // lo f16 dup
      const h2 hh = u2h(__builtin_amdgcn_perm(ap, ap, 0x03020302));  // hi f16 dup
#pragma unroll
      for (int qp=0; qp<4; ++qp)
#pragma unroll
        for (int p=0; p<2; ++p){
          const h2 bt = u2h(jt[qp][p]);
          s[qp][p] += __builtin_elementwise_max(hl + bt, z);
          s[qp][p] += __builtin_elementwise_max(hh + bt, z);
        }
    }
  // reduce over the 4 q-threads
#pragma unroll
  for (int m=0; m<2; ++m){
    const int msk = 16 << m;
#pragma unroll
    for (int qp=0; qp<4; ++qp)
#pragma unroll
      for (int p=0; p<2; ++p)
        s[qp][p] += u2h((u32)__shfl_xor((int)h2u_(s[qp][p]), msk));
  }
  // write own q-slot: local j = wm*16 + q*4 + 2p + {0,1}
#pragma unroll
  for (int qp=0; qp<4; ++qp) if (qp == q){
#pragma unroll
    for (int p=0; p<2; ++p){
      const int j = (wm<<4) + (qp<<2) + (p<<1);
      hu lo, hi; lo.h = s[qp][p].x; hi.h = s[qp][p].y;
      Q[j][n]   = lo.u;
      Q[j+1][n] = hi.u;
    }
  }
}

// pred(own 32 rows x 8) = hd @ dw2 + db2 -> global out (side branch, tid<256)
__device__ __forceinline__ void dec_out(const u16 (*S)[LDP], const u16* __restrict__ dwt,
    float db2v, float* __restrict__ out, int batch, int half, int t, int tid)
{
  const int r = tid>>3, d = tid&7;          // r local 0..31
  float acc = db2v;
#pragma unroll
  for (int c=0; c<16; ++c){
    f16x8 hv = *(const f16x8*)&S[r][c<<3];
    f16x8 wv = *(const f16x8*)(dwt + (d<<7) + (c<<3));
#pragma unroll
    for (int j=0; j<8; ++j)
      acc += (float)hv[j] * (float)wv[j];
  }
  out[(size_t)(batch*NSTEP + t)*(KK*DD) + ((half<<5)+r)*DD + d] = acc;
}

// h0 = relu(gt0 @ ew1 + eb1), full 64 rows (1024 threads: 8 rows each)
__device__ __forceinline__ void mlp_in8(const float* pred, const float* __restrict__ W,
    const float* __restrict__ bias, u16 (*O)[LDP], int tid)
{
  const int h = tid & 127, rg = tid >> 7;    // rg in [0,8)
  float wv[DD];
#pragma unroll
  for (int d=0; d<DD; ++d) wv[d] = W[d*HH + h];
  const float bv = bias[h];
  for (int rr=0; rr<8; ++rr){
    const int r = (rg<<3) + rr;
    float v = bv;
#pragma unroll
    for (int d=0; d<DD; ++d) v += pred[r*DD + d] * wv[d];
    O[r][h] = f2h_bits(fmaxf(v, 0.f));
  }
}

// ---------------- prep: fused fp32 weight products -> f16 frags (+ flag zeroing) ----------------
// VMEM-issue-optimized: each "heavy" thread computes 4 adjacent-nn outputs so the
// column-operand reads become one float4 per m (nn%4==0 -> 16B aligned) and the row
// scalar is reused 4x. Per-output m-accumulation order is UNCHANGED (bitwise-identical
// math to the serial version). Heavy segs: EWA/EWB/EWS, SUIU, UD. Light segs (DET K=8,
// dw2T, biases) keep the 1-output/thread mapping. Load instrs: ~25M -> ~6M.
__global__ void prep_kernel(
    const float* __restrict__ ew1, const float* __restrict__ eb1,
    const float* __restrict__ ew2, const float* __restrict__ eb2,
    const float* __restrict__ sw1, const float* __restrict__ sb1,
    const float* __restrict__ sw2, const float* __restrict__ sb2,
    const float* __restrict__ iw1, const float* __restrict__ ib1,
    const float* __restrict__ iw2, const float* __restrict__ ib2,
    const float* __restrict__ uw1, const float* __restrict__ ub1,
    const float* __restrict__ uw2, const float* __restrict__ ub2,
    const float* __restrict__ dw1, const float* __restrict__ db1,
    const float* __restrict__ dw2, const float* __restrict__ db2,
    u16* __restrict__ ws)
{
  const int t = blockIdx.x * 256 + threadIdx.x;
  if (t < 512) ((u32*)(ws + O_FLAG))[t] = 0;   // zero exchange flags each launch

  if (t < 24576){
    // ---- heavy quarter-threads: r' -> r with lane&3 == 0 (bits 3-4 of r zero) ----
    const float* A;        // row operand (contiguous in m)
    const float* B0;       // column operand base (row-major [*, 128])
    int base, r;
    float sc = 1.f;
    if (t < 12288){
      const int mat = t >> 12, rq = t & 4095;
      r = ((rq >> 3) << 5) | (rq & 7);
      const int kc = (r >> 9) & 3, lane = (r >> 3) & 63, e = r & 7;
      const int k  = (kc<<5) + ((lane>>4)<<3) + e;
      A  = ew2 + k*HH;
      B0 = (mat==0) ? iw1 : (mat==1) ? (iw1 + HH*HH) : sw1;
      base = mat*16384 + r;                      // O_EWA/O_EWB/O_EWS
    } else if (t < 20480){
      const int rq = t - 12288;                  // [0,8192)
      r = ((rq >> 3) << 5) | (rq & 7);
      const int kc = (r >> 9) & 7, lane = (r >> 3) & 63, e = r & 7;
      const int k  = ((kc&3)<<5) + ((lane>>4)<<3) + e;
      if (kc < 4){ A = sw2 + k*HH; B0 = uw1; }
      else       { A = iw2 + k*HH; B0 = uw1 + HH*HH; sc = 1.f/64.f; }
      base = O_SUIU + r;
    } else {
      const int rq = t - 20480;                  // [0,4096)
      r = ((rq >> 3) << 5) | (rq & 7);
      const int kc = (r >> 9) & 3, lane = (r >> 3) & 63, e = r & 7;
      const int k  = (kc<<5) + ((lane>>4)<<3) + e;
      A = uw2 + k*HH; B0 = dw1;
      base = O_UD + r;
    }
    const int g = (t < 12288) ? ((r >> 11) & 7)
                : (t < 20480) ? (r >> 12) : (r >> 11);
    const int nn = (g<<4) + ((r >> 3) & 15);     // nn % 4 == 0
    float s0=0.f, s1=0.f, s2=0.f, s3=0.f;
    for (int m=0; m<HH; ++m){
      const float a = A[m];
      const float4 b = *(const float4*)(B0 + m*HH + nn);
      s0 += a*b.x; s1 += a*b.y; s2 += a*b.z; s3 += a*b.w;
    }
    hu h0,h1,h2_,h3;
    h0.h=(f16)(s0*sc); h1.h=(f16)(s1*sc); h2_.h=(f16)(s2*sc); h3.h=(f16)(s3*sc);
    ws[base]    = h0.u;  ws[base+8]  = h1.u;     // nn+1 <-> r+8
    ws[base+16] = h2_.u; ws[base+24] = h3.u;
  } else if (t < 42752){
    // ---- light region: idx in [98304, 116480) ----
    const int idx = 98304 + (t - 24576);
    if (idx < 114688){
      // DET frags: DE = dw2 @ ew1  (K=8 inner)
      const int r = idx - 98304;
      const int g = r >> 11, kc = (r >> 9) & 3, lane = (r >> 3) & 63, e = r & 7;
      const int k  = (kc<<5) + ((lane>>4)<<3) + e;
      const int nn = (g<<4) + (lane & 15);
      float v = 0.f;
#pragma unroll
      for (int d=0; d<DD; ++d) v += dw2[k*DD+d] * ew1[d*HH+nn];
      hu hb; hb.h = (f16)v; ws[idx] = hb.u;
    } else if (idx < 115712){
      const int r = idx - 114688, d = r >> 7, hcol = r & 127;   // dw2T [8][128]
      hu hb; hb.h = (f16)dw2[hcol*DD + d]; ws[idx] = hb.u;
    } else if (idx < 116480){
      // fused biases (f32)
      const int j = idx - 115712, which = j >> 7, nn = j & 127;
      float v = 0.f;
      switch (which){
        case 0: for (int m=0; m<HH; ++m) v += eb2[m] * iw1[m*HH+nn]; break;                  // bA
        case 1: for (int m=0; m<HH; ++m) v += eb2[m] * iw1[(HH+m)*HH+nn]; v += ib1[nn]; break; // bB
        case 2: for (int m=0; m<HH; ++m) v += eb2[m] * sw1[m*HH+nn]; v += sb1[nn]; break;    // bS
        case 3: for (int m=0; m<HH; ++m) v += sb2[m]*uw1[m*HH+nn] + ib2[m]*uw1[(HH+m)*HH+nn];
                v += ub1[nn]; break;                                                          // bU
        case 4: for (int m=0; m<HH; ++m) v += ub2[m] * dw1[m*HH+nn]; v += db1[nn]; break;    // bUD
        default:
#pragma unroll
          for (int d=0; d<DD; ++d) v += db2[d] * ew1[d*HH+nn];
          v += eb1[nn]; break;                                                                // deb
      }
      ((float*)ws)[BIASF + j] = v;
    }
  }
}

// ---------------- rollout: 2 blocks / batch (256 blocks, 1/CU), 1024 threads (4 waves/SIMD) ----------------
// EXACT round-7 structure -- the measured optimum of this family (82.4us rollout):
// pairwise same-XCD exchange via LDS import, block-wide tid0 acquire-spin. All attempted
// deviations regressed: 4-way exchange (r6, 200us), per-wave spin / xbuf-direct reads
// (r8/r9, 237/112us: L1-invalidate thrash + 16x read amplification), register-persistent
// B-frags (r10, 98us: compiler demoted them to scratch -- FETCH 3.9->37MB).
__global__ __launch_bounds__(1024, 1) void rollout_kernel(
    const float* __restrict__ gt, const int* __restrict__ rollout,
    const float* __restrict__ ew1, const float* __restrict__ eb1,
    const float* __restrict__ db2,
    u16* __restrict__ ws, float* __restrict__ out)
{
  extern __shared__ u16 smem[];
  u16 (*P)[LDP] = (u16(*)[LDP])smem;                 // full h: 64 rows
  u16 (*Q)[LDP] = (u16(*)[LDP])(smem + 64*LDP);      // Ssum own half: 32 rows
  u16 (*R)[LDP] = (u16(*)[LDP])(smem + 96*LDP);      // hu own half: 32 rows
  u16 (*S)[LDP] = (u16(*)[LDP])(smem + 128*LDP);     // hs/hd own half: 32 rows
  float* predbuf = (float*)Q;                        // 512 f32, init only

  const int tid = threadIdx.x, blk = blockIdx.x;
  const int batch = blk & 127, half = blk >> 7;      // partner blk^128 -> same XCD
  const int w = tid >> 6, lane = tid & 63;
  const int l15 = lane & 15, q = lane >> 4;
  const int wn = w & 7, wm = w >> 3;
  const int n = (wn << 4) + l15;

  int ns = rollout[0];
  if (ns > TT-1) ns = TT-1;
  if (ns > NSTEP) ns = NSTEP;
  if (ns < 0) ns = 0;

  // fused per-thread biases (col n)
  const float* bf32 = (const float*)ws;
  const float bAv  = bf32[BIASF + n];
  const float bBv  = bf32[BIASF + 128 + n];
  const float bSv  = bf32[BIASF + 256 + n];
  const float bUv  = bf32[BIASF + 384 + n];
  const float bUDv = bf32[BIASF + 512 + n];
  const float debv = bf32[BIASF + 640 + n];
  const float db2v = db2[tid & 7];

  // exchange bookkeeping
  u16* xbuf  = ws + O_XBUF;
  u32* flags = (u32*)(ws + O_FLAG);
  const int own  = (batch<<1) + half;
  const int prt  = (batch<<1) + (1-half);

  // init: targets copy (own half share) + h0 = relu(gt[:,0]@ew1 + eb1) (full)
  for (int i = tid; i < (NSTEP*KK*DD/2); i += 1024)
    out[PREDSZ + batch*(NSTEP*KK*DD) + half*(NSTEP*KK*DD/2) + i]
      = gt[(size_t)batch*(TT*KK*DD) + KK*DD + half*(NSTEP*KK*DD/2) + i];
  if (tid < KK*DD) predbuf[tid] = gt[(size_t)batch*(TT*KK*DD) + tid];
  __syncthreads();
  mlp_in8(predbuf, ew1, eb1, P, tid);               // P = h0 (64 rows)
  __syncthreads();

  for (int t=0; t<ns; ++t){
    fusedS1I(P, ws, bAv, bBv, bSv, Q, S, wn, wm, half, l15, q, n, lane); // Q=Ssum, S=hs (32)
    __syncthreads();
    gemm256_16(S, Q, ws+O_SUIU, bUv, R, wn, wm, l15, q, n, lane);  // R = hu (32)
    __syncthreads();
    gemm16<true>(R, ws+O_UD, bUDv, S, wn, wm, l15, q, n, lane);    // S = hd (32)
    __syncthreads();
    // DET: h_next own rows -> P (+ fused export to xbuf)
    {
      f16x8 bfw[4];
#pragma unroll
      for (int kc=0; kc<4; ++kc)
        bfw[kc] = *(const f16x8*)(ws + O_DET + (wn<<11) + (kc<<9) + (lane<<3));
      f32x4 acc = {0.f,0.f,0.f,0.f};
#pragma unroll
      for (int kc=0; kc<4; ++kc){
        f16x8 af = *(const f16x8*)&S[(wm<<4)+l15][(kc<<5)+(q<<3)];
        acc = __builtin_amdgcn_mfma_f32_16x16x32_f16(af, bfw[kc], acc, 0,0,0);
      }
      const int par = t & 1;
      u16* ob = xbuf + (((own<<1)|par)<<12);
      const bool exch = (t < ns-1);
#pragma unroll
      for (int e=0; e<4; ++e){
        const u16 bits = f2h_bits(fmaxf(acc[e]+debv, 0.f));
        const int lr = (wm<<4)+(q<<2)+e;               // local row in half (0..31)
        P[(half<<5)+lr][n] = bits;
        if (exch) ob[(lr<<7) | n] = bits;
      }
    }
    if (tid < 256) dec_out(S, ws+O_DW2T, db2v, out, batch, half, t, tid);
    __syncthreads();

    if (t < ns-1){
      const int par = t & 1;
      if (tid == 0){
        __hip_atomic_store(&flags[(own<<1)|par], (u32)(t+1),
                           __ATOMIC_RELEASE, __HIP_MEMORY_SCOPE_AGENT);
        int guard = 0;
        while (__hip_atomic_load(&flags[(prt<<1)|par],
                 __ATOMIC_ACQUIRE, __HIP_MEMORY_SCOPE_AGENT) != (u32)(t+1)
               && guard < (1<<22)){
          ++guard;
          __builtin_amdgcn_s_sleep(1);
        }
      }
      __syncthreads();
      // import partner half into P
      if (tid < 512){
        const u16* pb = xbuf + (((prt<<1)|par)<<12);
        const int r = tid >> 4, c = (tid & 15) << 3;
        *(f16x8*)&P[((1-half)<<5)+r][c] = *(const f16x8*)(pb + (r<<7) + c);
      }
      __syncthreads();
    }
  }
}

extern "C" void kernel_launch(void* const* d_in, const int* in_sizes, int n_in,
                              void* d_out, int out_size, void* d_ws, size_t ws_size,
                              hipStream_t stream)
{
  const float* gt  = (const float*)d_in[0];
  const int*   rs  = (const int*)d_in[1];
  const float* ew1 = (const float*)d_in[2];
  const float* eb1 = (const float*)d_in[3];
  const float* ew2 = (const float*)d_in[4];
  const float* eb2 = (const float*)d_in[5];
  const float* sw1 = (const float*)d_in[6];
  const float* sb1 = (const float*)d_in[7];
  const float* sw2 = (const float*)d_in[8];
  const float* sb2 = (const float*)d_in[9];
  const float* iw1 = (const float*)d_in[10];
  const float* ib1 = (const float*)d_in[11];
  const float* iw2 = (const float*)d_in[12];
  const float* ib2 = (const float*)d_in[13];
  const float* uw1 = (const float*)d_in[14];
  const float* ub1 = (const float*)d_in[15];
  const float* uw2 = (const float*)d_in[16];
  const float* ub2 = (const float*)d_in[17];
  const float* dw1 = (const float*)d_in[18];
  const float* db1 = (const float*)d_in[19];
  const float* dw2 = (const float*)d_in[20];
  const float* db2 = (const float*)d_in[21];
  float* out = (float*)d_out;
  u16*   ws  = (u16*)d_ws;

  const int smem_bytes = 160 * LDP * (int)sizeof(u16);  // 43520
  (void)hipFuncSetAttribute((const void*)rollout_kernel,
                            hipFuncAttributeMaxDynamicSharedMemorySize, smem_bytes);

  hipLaunchKernelGGL(prep_kernel, dim3(167), dim3(256), 0, stream,
                     ew1, eb1, ew2, eb2, sw1, sb1, sw2, sb2, iw1, ib1, iw2, ib2,
                     uw1, ub1, uw2, ub2, dw1, db1, dw2, db2, ws);
  hipLaunchKernelGGL(rollout_kernel, dim3(2*BB), dim3(1024), smem_bytes, stream,
                     gt, rs, ew1, eb1, db2, ws, out);
}

// Round 12
// 201.414 us; speedup vs baseline: 1.0087x; 1.0087x over previous
//
#include <hip/hip_runtime.h>

// Problem constants
#define BB 128
#define TT 6
#define KK 64
#define DD 8
#define HH 128
#define NSTEP 5
#define LDP 136      // padded LDS row (u16 elems): 272B = 17*16B, 16B-aligned rows
#define PREDSZ (BB*NSTEP*KK*DD)   // 327680

typedef unsigned short u16;
typedef unsigned int   u32;
typedef _Float16 f16;
typedef __attribute__((ext_vector_type(8))) _Float16 f16x8;
typedef __attribute__((ext_vector_type(4))) float f32x4;
typedef __attribute__((ext_vector_type(2))) _Float16 h2;

union h2u { u32 u; h2 h; };
union hu  { u16 u; f16 h; };

__device__ __forceinline__ u16 f2h_bits(float f){
  hu v; v.h = (f16)f; return v.u;     // v_cvt_f16_f32, 1 instr
}
__device__ __forceinline__ u32 pk2(float x, float y){  // two cvts + pack
  hu a, b; a.h = (f16)x; b.h = (f16)y;
  return (u32)a.u | ((u32)b.u << 16);
}
__device__ __forceinline__ h2 u2h(u32 x){ h2u t; t.u = x; return t.h; }
__device__ __forceinline__ u32 h2u_(h2 x){ h2u t; t.h = x; return t.u; }

// ---------------- ws layout (u16 element offsets) ----------------
// Fused weight matrices (exact fp32 products, cast f16), wave-coalesced frags:
//   FR[g=8][kc=4][lane=64][8] : elem off = g*2048 + kc*512 + lane*8
// SUIU (K=256): FR[g=8][kc=8][lane=64][8], kc<4 = SU rows, kc>=4 = IU rows.
#define O_EWA   0        // ew2 @ wi_a
#define O_EWB   16384    // ew2 @ wi_b
#define O_EWS   32768    // ew2 @ self_w1
#define O_SUIU  49152    // [self_w2 @ uw1_top | (inter_w2 @ uw1_bot)/64]  (32768 elems)
#define O_UD    81920    // upd_w2 @ dec_w1
#define O_DET   98304    // dec_w2 @ enc_w1
#define O_DW2T  114688   // dw2 transposed f16 [8][128]
#define BIASF   57856    // float idx: bA,bB,bS,bU,bUD,deb  (6 x 128 f32)
// pair-exchange region:
#define O_XBUF  131072                    // u16: [pairslot=batch*2+half][slot=2][4096]
#define O_FLAG  (O_XBUF + 128*2*2*4096)   // u16 offset of u32 flags[256][2]

// ---- 16-row GEMM: O(16 local rows x 128) = A@W [+ bias]; wave (wn,wm) -> 16 cols, 1 m-tile ----
// A, O are 32-row local buffers; rows (wm<<4)+...
template<bool RELU>
__device__ __forceinline__ void gemm16(const u16 (*A)[LDP], const u16* __restrict__ wt,
    float bias, u16 (*O)[LDP], int wn, int wm, int l15, int q, int n, int lane)
{
  f16x8 bf[4];
#pragma unroll
  for (int kc=0; kc<4; ++kc)
    bf[kc] = *(const f16x8*)(wt + (wn<<11) + (kc<<9) + (lane<<3));
  f32x4 acc = {0.f,0.f,0.f,0.f};
#pragma unroll
  for (int kc=0; kc<4; ++kc){
    f16x8 af = *(const f16x8*)&A[(wm<<4)+l15][(kc<<5)+(q<<3)];
    acc = __builtin_amdgcn_mfma_f32_16x16x32_f16(af, bf[kc], acc, 0,0,0);
  }
#pragma unroll
  for (int e=0; e<4; ++e){
    float v = acc[e] + bias;
    if (RELU) v = fmaxf(v, 0.f);
    O[(wm<<4)+(q<<2)+e][n] = f2h_bits(v);   // C/D: col=lane&15, row=q*4+e
  }
}

// K=256: O(16 local rows) = relu([A1 | A2] @ [SU|IU] + bU); A1/A2 32-row local buffers
__device__ __forceinline__ void gemm256_16(const u16 (*A1)[LDP], const u16 (*A2)[LDP],
    const u16* __restrict__ wt, float bias, u16 (*O)[LDP], int wn, int wm, int l15, int q, int n, int lane)
{
  f16x8 bf[8];
#pragma unroll
  for (int kc=0; kc<8; ++kc)
    bf[kc] = *(const f16x8*)(wt + (wn<<12) + (kc<<9) + (lane<<3));
  f32x4 acc = {0.f,0.f,0.f,0.f};
#pragma unroll
  for (int kc=0; kc<8; ++kc){
    const u16 (*As)[LDP] = (kc<4) ? A1 : A2;
    f16x8 af = *(const f16x8*)&As[(wm<<4)+l15][((kc&3)<<5)+(q<<3)];
    acc = __builtin_amdgcn_mfma_f32_16x16x32_f16(af, bf[kc], acc, 0,0,0);
  }
#pragma unroll
  for (int e=0; e<4; ++e){
    float v = fmaxf(acc[e] + bias, 0.f);
    O[(wm<<4)+(q<<2)+e][n] = f2h_bits(v);
  }
}

// ---- Fused stage1 + interaction, 16-wave pair-split version ----
// Block (batch,half) holds FULL h (64 rows) in P. Wave (wn,wm) computes:
//   a = h@EWA for ALL 64 rows x its 16 cols (full height required by sum over i);
//   b, hs only for its own 16 rows (global rows rowbase = half*32 + wm*16);
//   interaction Ssum[j,n] = sum_i relu(a[i,n]+b[j,n]) for its own 16 j's, wave-locally.
__device__ __forceinline__ void fusedS1I(const u16 (*P)[LDP], const u16* __restrict__ ws,
    float bAv, float bBv, float bSv,
    u16 (*Q)[LDP], u16 (*S)[LDP],
    int wn, int wm, int half, int l15, int q, int n, int lane)
{
  const int rowbase = (half<<5) + (wm<<4);
  u32 aPk[4][2];   // [mt][pair]: a rows mt*16+q*4+{2p,2p+1}, col n (f16 pairs)
  {
    f16x8 fa[4];
#pragma unroll
    for (int kc=0; kc<4; ++kc)
      fa[kc] = *(const f16x8*)(ws + O_EWA + (wn<<11) + (kc<<9) + (lane<<3));
#pragma unroll
    for (int mt=0; mt<4; ++mt){
      f32x4 aA = {0.f,0.f,0.f,0.f};
#pragma unroll
      for (int kc=0; kc<4; ++kc){
        f16x8 af = *(const f16x8*)&P[(mt<<4)+l15][(kc<<5)+(q<<3)];
        aA = __builtin_amdgcn_mfma_f32_16x16x32_f16(af, fa[kc], aA, 0,0,0);
      }
      aPk[mt][0] = pk2(aA[0]+bAv, aA[1]+bAv);
      aPk[mt][1] = pk2(aA[2]+bAv, aA[3]+bAv);
    }
  }
  u32 bPk[2];
  {
    f16x8 fb[4], fs[4], af[4];
#pragma unroll
    for (int kc=0; kc<4; ++kc){
      const int o = (wn<<11) + (kc<<9) + (lane<<3);
      fb[kc] = *(const f16x8*)(ws + O_EWB + o);
      fs[kc] = *(const f16x8*)(ws + O_EWS + o);
      af[kc] = *(const f16x8*)&P[rowbase+l15][(kc<<5)+(q<<3)];
    }
    f32x4 aB = {0.f,0.f,0.f,0.f}, aS = {0.f,0.f,0.f,0.f};
#pragma unroll
    for (int kc=0; kc<4; ++kc){
      aB = __builtin_amdgcn_mfma_f32_16x16x32_f16(af[kc], fb[kc], aB, 0,0,0);
      aS = __builtin_amdgcn_mfma_f32_16x16x32_f16(af[kc], fs[kc], aS, 0,0,0);
    }
    bPk[0] = pk2(aB[0]+bBv, aB[1]+bBv);
    bPk[1] = pk2(aB[2]+bBv, aB[3]+bBv);
#pragma unroll
    for (int e=0; e<4; ++e)
      S[(wm<<4)+(q<<2)+e][n] = f2h_bits(fmaxf(aS[e]+bSv, 0.f));
  }

  // gather the 16 own b's across q-lanes
  u32 jt[4][2];
#pragma unroll
  for (int qp=0; qp<4; ++qp){
    const int src = (qp<<4) + l15;
    jt[qp][0] = (u32)__shfl((int)bPk[0], src);
    jt[qp][1] = (u32)__shfl((int)bPk[1], src);
  }
  h2 z; z.x = (f16)0.f; z.y = (f16)0.f;
  h2 s[4][2];
#pragma unroll
  for (int qp=0; qp<4; ++qp){ s[qp][0] = z; s[qp][1] = z; }
  // accumulate over this thread's 16 i-values (4 mt x 2 pairs x 2 f16)
#pragma unroll
  for (int mt=0; mt<4; ++mt)
#pragma unroll
    for (int pp=0; pp<2; ++pp){
      const u32 ap = aPk[mt][pp];
      const h2 hl = u2h(__builtin_amdgcn_perm(ap, ap, 0x01000100));  // lo f16 dup
      const h2 hh = u2h(__builtin_amdgcn_perm(ap, ap, 0x03020302));  // hi f16 dup
#pragma unroll
      for (int qp=0; qp<4; ++qp)
#pragma unroll
        for (int p=0; p<2; ++p){
          const h2 bt = u2h(jt[qp][p]);
          s[qp][p] += __builtin_elementwise_max(hl + bt, z);
          s[qp][p] += __builtin_elementwise_max(hh + bt, z);
        }
    }
  // reduce over the 4 q-threads
#pragma unroll
  for (int m=0; m<2; ++m){
    const int msk = 16 << m;
#pragma unroll
    for (int qp=0; qp<4; ++qp)
#pragma unroll
      for (int p=0; p<2; ++p)
        s[qp][p] += u2h((u32)__shfl_xor((int)h2u_(s[qp][p]), msk));
  }
  // write own q-slot: local j = wm*16 + q*4 + 2p + {0,1}
#pragma unroll
  for (int qp=0; qp<4; ++qp) if (qp == q){
#pragma unroll
    for (int p=0; p<2; ++p){
      const int j = (wm<<4) + (qp<<2) + (p<<1);
      hu lo, hi; lo.h = s[qp][p].x; hi.h = s[qp][p].y;
      Q[j][n]   = lo.u;
      Q[j+1][n] = hi.u;
    }
  }
}

// pred(own 32 rows x 8) = hd @ dw2 + db2 -> global out (side branch, tid<256)
__device__ __forceinline__ void dec_out(const u16 (*S)[LDP], const u16* __restrict__ dwt,
    float db2v, float* __restrict__ out, int batch, int half, int t, int tid)
{
  const int r = tid>>3, d = tid&7;          // r local 0..31
  float acc = db2v;
#pragma unroll
  for (int c=0; c<16; ++c){
    f16x8 hv = *(const f16x8*)&S[r][c<<3];
    f16x8 wv = *(const f16x8*)(dwt + (d<<7) + (c<<3));
#pragma unroll
    for (int j=0; j<8; ++j)
      acc += (float)hv[j] * (float)wv[j];
  }
  out[(size_t)(batch*NSTEP + t)*(KK*DD) + ((half<<5)+r)*DD + d] = acc;
}

// h0 = relu(gt0 @ ew1 + eb1), full 64 rows (1024 threads: 8 rows each)
__device__ __forceinline__ void mlp_in8(const float* pred, const float* __restrict__ W,
    const float* __restrict__ bias, u16 (*O)[LDP], int tid)
{
  const int h = tid & 127, rg = tid >> 7;    // rg in [0,8)
  float wv[DD];
#pragma unroll
  for (int d=0; d<DD; ++d) wv[d] = W[d*HH + h];
  const float bv = bias[h];
  for (int rr=0; rr<8; ++rr){
    const int r = (rg<<3) + rr;
    float v = bv;
#pragma unroll
    for (int d=0; d<DD; ++d) v += pred[r*DD + d] * wv[d];
    O[r][h] = f2h_bits(fmaxf(v, 0.f));
  }
}

// ---------------- prep: fused fp32 weight products -> f16 frags (+ flag zeroing) ----------------
// r11 mapping (verified correct) with the ILP repaired: r11's 4-wide threads were
// latency-bound (96 heavy blocks -> 1 wave/SIMD, scalar A loads, no unroll -> ~26us).
// Now: A loaded as float4 (contiguous in m, 16B aligned), m unrolled by 4 with all 5
// vec4 loads issued per group, #pragma unroll 2 on top -> ~10 loads in flight/thread.
// Per-output accumulation order stays ascending-m (sequential +=).
__global__ void prep_kernel(
    const float* __restrict__ ew1, const float* __restrict__ eb1,
    const float* __restrict__ ew2, const float* __restrict__ eb2,
    const float* __restrict__ sw1, const float* __restrict__ sb1,
    const float* __restrict__ sw2, const float* __restrict__ sb2,
    const float* __restrict__ iw1, const float* __restrict__ ib1,
    const float* __restrict__ iw2, const float* __restrict__ ib2,
    const float* __restrict__ uw1, const float* __restrict__ ub1,
    const float* __restrict__ uw2, const float* __restrict__ ub2,
    const float* __restrict__ dw1, const float* __restrict__ db1,
    const float* __restrict__ dw2, const float* __restrict__ db2,
    u16* __restrict__ ws)
{
  const int t = blockIdx.x * 256 + threadIdx.x;
  if (t < 512) ((u32*)(ws + O_FLAG))[t] = 0;   // zero exchange flags each launch

  if (t < 24576){
    // ---- heavy quarter-threads: r' -> r with lane&3 == 0 (bits 3-4 of r zero) ----
    const float* A;        // row operand (contiguous in m)
    const float* B0;       // column operand base (row-major [*, 128])
    int base, r;
    float sc = 1.f;
    if (t < 12288){
      const int mat = t >> 12, rq = t & 4095;
      r = ((rq >> 3) << 5) | (rq & 7);
      const int kc = (r >> 9) & 3, lane = (r >> 3) & 63, e = r & 7;
      const int k  = (kc<<5) + ((lane>>4)<<3) + e;
      A  = ew2 + k*HH;
      B0 = (mat==0) ? iw1 : (mat==1) ? (iw1 + HH*HH) : sw1;
      base = mat*16384 + r;                      // O_EWA/O_EWB/O_EWS
    } else if (t < 20480){
      const int rq = t - 12288;                  // [0,8192)
      r = ((rq >> 3) << 5) | (rq & 7);
      const int kc = (r >> 9) & 7, lane = (r >> 3) & 63, e = r & 7;
      const int k  = ((kc&3)<<5) + ((lane>>4)<<3) + e;
      if (kc < 4){ A = sw2 + k*HH; B0 = uw1; }
      else       { A = iw2 + k*HH; B0 = uw1 + HH*HH; sc = 1.f/64.f; }
      base = O_SUIU + r;
    } else {
      const int rq = t - 20480;                  // [0,4096)
      r = ((rq >> 3) << 5) | (rq & 7);
      const int kc = (r >> 9) & 3, lane = (r >> 3) & 63, e = r & 7;
      const int k  = (kc<<5) + ((lane>>4)<<3) + e;
      A = uw2 + k*HH; B0 = dw1;
      base = O_UD + r;
    }
    const int g = (t < 12288) ? ((r >> 11) & 7)
                : (t < 20480) ? (r >> 12) : (r >> 11);
    const int nn = (g<<4) + ((r >> 3) & 15);     // nn % 4 == 0
    float s0=0.f, s1=0.f, s2=0.f, s3=0.f;
#pragma unroll 2
    for (int m=0; m<HH; m+=4){
      const float4 a4 = *(const float4*)(A + m);
      const float4 b0 = *(const float4*)(B0 + (m+0)*HH + nn);
      const float4 b1 = *(const float4*)(B0 + (m+1)*HH + nn);
      const float4 b2 = *(const float4*)(B0 + (m+2)*HH + nn);
      const float4 b3 = *(const float4*)(B0 + (m+3)*HH + nn);
      s0 += a4.x*b0.x; s1 += a4.x*b0.y; s2 += a4.x*b0.z; s3 += a4.x*b0.w;
      s0 += a4.y*b1.x; s1 += a4.y*b1.y; s2 += a4.y*b1.z; s3 += a4.y*b1.w;
      s0 += a4.z*b2.x; s1 += a4.z*b2.y; s2 += a4.z*b2.z; s3 += a4.z*b2.w;
      s0 += a4.w*b3.x; s1 += a4.w*b3.y; s2 += a4.w*b3.z; s3 += a4.w*b3.w;
    }
    hu h0,h1,h2_,h3;
    h0.h=(f16)(s0*sc); h1.h=(f16)(s1*sc); h2_.h=(f16)(s2*sc); h3.h=(f16)(s3*sc);
    ws[base]    = h0.u;  ws[base+8]  = h1.u;     // nn+1 <-> r+8
    ws[base+16] = h2_.u; ws[base+24] = h3.u;
  } else if (t < 42752){
    // ---- light region: idx in [98304, 116480) ----
    const int idx = 98304 + (t - 24576);
    if (idx < 114688){
      // DET frags: DE = dw2 @ ew1  (K=8 inner)
      const int r = idx - 98304;
      const int g = r >> 11, kc = (r >> 9) & 3, lane = (r >> 3) & 63, e = r & 7;
      const int k  = (kc<<5) + ((lane>>4)<<3) + e;
      const int nn = (g<<4) + (lane & 15);
      float v = 0.f;
#pragma unroll
      for (int d=0; d<DD; ++d) v += dw2[k*DD+d] * ew1[d*HH+nn];
      hu hb; hb.h = (f16)v; ws[idx] = hb.u;
    } else if (idx < 115712){
      const int r = idx - 114688, d = r >> 7, hcol = r & 127;   // dw2T [8][128]
      hu hb; hb.h = (f16)dw2[hcol*DD + d]; ws[idx] = hb.u;
    } else if (idx < 116480){
      // fused biases (f32)
      const int j = idx - 115712, which = j >> 7, nn = j & 127;
      float v = 0.f;
      switch (which){
        case 0: for (int m=0; m<HH; ++m) v += eb2[m] * iw1[m*HH+nn]; break;                  // bA
        case 1: for (int m=0; m<HH; ++m) v += eb2[m] * iw1[(HH+m)*HH+nn]; v += ib1[nn]; break; // bB
        case 2: for (int m=0; m<HH; ++m) v += eb2[m] * sw1[m*HH+nn]; v += sb1[nn]; break;    // bS
        case 3: for (int m=0; m<HH; ++m) v += sb2[m]*uw1[m*HH+nn] + ib2[m]*uw1[(HH+m)*HH+nn];
                v += ub1[nn]; break;                                                          // bU
        case 4: for (int m=0; m<HH; ++m) v += ub2[m] * dw1[m*HH+nn]; v += db1[nn]; break;    // bUD
        default:
#pragma unroll
          for (int d=0; d<DD; ++d) v += db2[d] * ew1[d*HH+nn];
          v += eb1[nn]; break;                                                                // deb
      }
      ((float*)ws)[BIASF + j] = v;
    }
  }
}

// ---------------- rollout: 2 blocks / batch (256 blocks, 1/CU), 1024 threads (4 waves/SIMD) ----------------
// EXACT round-7 structure -- the measured optimum of this family (82.4us rollout):
// pairwise same-XCD exchange via LDS import, block-wide tid0 acquire-spin. All attempted
// deviations regressed: 4-way exchange (r6, 200us), per-wave spin / xbuf-direct reads
// (r8/r9, 237/112us: L1-invalidate thrash + 16x read amplification), register-persistent
// B-frags (r10, 98us: compiler demoted them to scratch -- FETCH 3.9->37MB).
__global__ __launch_bounds__(1024, 1) void rollout_kernel(
    const float* __restrict__ gt, const int* __restrict__ rollout,
    const float* __restrict__ ew1, const float* __restrict__ eb1,
    const float* __restrict__ db2,
    u16* __restrict__ ws, float* __restrict__ out)
{
  extern __shared__ u16 smem[];
  u16 (*P)[LDP] = (u16(*)[LDP])smem;                 // full h: 64 rows
  u16 (*Q)[LDP] = (u16(*)[LDP])(smem + 64*LDP);      // Ssum own half: 32 rows
  u16 (*R)[LDP] = (u16(*)[LDP])(smem + 96*LDP);      // hu own half: 32 rows
  u16 (*S)[LDP] = (u16(*)[LDP])(smem + 128*LDP);     // hs/hd own half: 32 rows
  float* predbuf = (float*)Q;                        // 512 f32, init only

  const int tid = threadIdx.x, blk = blockIdx.x;
  const int batch = blk & 127, half = blk >> 7;      // partner blk^128 -> same XCD
  const int w = tid >> 6, lane = tid & 63;
  const int l15 = lane & 15, q = lane >> 4;
  const int wn = w & 7, wm = w >> 3;
  const int n = (wn << 4) + l15;

  int ns = rollout[0];
  if (ns > TT-1) ns = TT-1;
  if (ns > NSTEP) ns = NSTEP;
  if (ns < 0) ns = 0;

  // fused per-thread biases (col n)
  const float* bf32 = (const float*)ws;
  const float bAv  = bf32[BIASF + n];
  const float bBv  = bf32[BIASF + 128 + n];
  const float bSv  = bf32[BIASF + 256 + n];
  const float bUv  = bf32[BIASF + 384 + n];
  const float bUDv = bf32[BIASF + 512 + n];
  const float debv = bf32[BIASF + 640 + n];
  const float db2v = db2[tid & 7];

  // exchange bookkeeping
  u16* xbuf  = ws + O_XBUF;
  u32* flags = (u32*)(ws + O_FLAG);
  const int own  = (batch<<1) + half;
  const int prt  = (batch<<1) + (1-half);

  // init: targets copy (own half share) + h0 = relu(gt[:,0]@ew1 + eb1) (full)
  for (int i = tid; i < (NSTEP*KK*DD/2); i += 1024)
    out[PREDSZ + batch*(NSTEP*KK*DD) + half*(NSTEP*KK*DD/2) + i]
      = gt[(size_t)batch*(TT*KK*DD) + KK*DD + half*(NSTEP*KK*DD/2) + i];
  if (tid < KK*DD) predbuf[tid] = gt[(size_t)batch*(TT*KK*DD) + tid];
  __syncthreads();
  mlp_in8(predbuf, ew1, eb1, P, tid);               // P = h0 (64 rows)
  __syncthreads();

  for (int t=0; t<ns; ++t){
    fusedS1I(P, ws, bAv, bBv, bSv, Q, S, wn, wm, half, l15, q, n, lane); // Q=Ssum, S=hs (32)
    __syncthreads();
    gemm256_16(S, Q, ws+O_SUIU, bUv, R, wn, wm, l15, q, n, lane);  // R = hu (32)
    __syncthreads();
    gemm16<true>(R, ws+O_UD, bUDv, S, wn, wm, l15, q, n, lane);    // S = hd (32)
    __syncthreads();
    // DET: h_next own rows -> P (+ fused export to xbuf)
    {
      f16x8 bfw[4];
#pragma unroll
      for (int kc=0; kc<4; ++kc)
        bfw[kc] = *(const f16x8*)(ws + O_DET + (wn<<11) + (kc<<9) + (lane<<3));
      f32x4 acc = {0.f,0.f,0.f,0.f};
#pragma unroll
      for (int kc=0; kc<4; ++kc){
        f16x8 af = *(const f16x8*)&S[(wm<<4)+l15][(kc<<5)+(q<<3)];
        acc = __builtin_amdgcn_mfma_f32_16x16x32_f16(af, bfw[kc], acc, 0,0,0);
      }
      const int par = t & 1;
      u16* ob = xbuf + (((own<<1)|par)<<12);
      const bool exch = (t < ns-1);
#pragma unroll
      for (int e=0; e<4; ++e){
        const u16 bits = f2h_bits(fmaxf(acc[e]+debv, 0.f));
        const int lr = (wm<<4)+(q<<2)+e;               // local row in half (0..31)
        P[(half<<5)+lr][n] = bits;
        if (exch) ob[(lr<<7) | n] = bits;
      }
    }
    if (tid < 256) dec_out(S, ws+O_DW2T, db2v, out, batch, half, t, tid);
    __syncthreads();

    if (t < ns-1){
      const int par = t & 1;
      if (tid == 0){
        __hip_atomic_store(&flags[(own<<1)|par], (u32)(t+1),
                           __ATOMIC_RELEASE, __HIP_MEMORY_SCOPE_AGENT);
        int guard = 0;
        while (__hip_atomic_load(&flags[(prt<<1)|par],
                 __ATOMIC_ACQUIRE, __HIP_MEMORY_SCOPE_AGENT) != (u32)(t+1)
               && guard < (1<<22)){
          ++guard;
          __builtin_amdgcn_s_sleep(1);
        }
      }
      __syncthreads();
      // import partner half into P
      if (tid < 512){
        const u16* pb = xbuf + (((prt<<1)|par)<<12);
        const int r = tid >> 4, c = (tid & 15) << 3;
        *(f16x8*)&P[((1-half)<<5)+r][c] = *(const f16x8*)(pb + (r<<7) + c);
      }
      __syncthreads();
    }
  }
}

extern "C" void kernel_launch(void* const* d_in, const int* in_sizes, int n_in,
                              void* d_out, int out_size, void* d_ws, size_t ws_size,
                              hipStream_t stream)
{
  const float* gt  = (const float*)d_in[0];
  const int*   rs  = (const int*)d_in[1];
  const float* ew1 = (const float*)d_in[2];
  const float* eb1 = (const float*)d_in[3];
  const float* ew2 = (const float*)d_in[4];
  const float* eb2 = (const float*)d_in[5];
  const float* sw1 = (const float*)d_in[6];
  const float* sb1 = (const float*)d_in[7];
  const float* sw2 = (const float*)d_in[8];
  const float* sb2 = (const float*)d_in[9];
  const float* iw1 = (const float*)d_in[10];
  const float* ib1 = (const float*)d_in[11];
  const float* iw2 = (const float*)d_in[12];
  const float* ib2 = (const float*)d_in[13];
  const float* uw1 = (const float*)d_in[14];
  const float* ub1 = (const float*)d_in[15];
  const float* uw2 = (const float*)d_in[16];
  const float* ub2 = (const float*)d_in[17];
  const float* dw1 = (const float*)d_in[18];
  const float* db1 = (const float*)d_in[19];
  const float* dw2 = (const float*)d_in[20];
  const float* db2 = (const float*)d_in[21];
  float* out = (float*)d_out;
  u16*   ws  = (u16*)d_ws;

  const int smem_bytes = 160 * LDP * (int)sizeof(u16);  // 43520
  (void)hipFuncSetAttribute((const void*)rollout_kernel,
                            hipFuncAttributeMaxDynamicSharedMemorySize, smem_bytes);

  hipLaunchKernelGGL(prep_kernel, dim3(167), dim3(256), 0, stream,
                     ew1, eb1, ew2, eb2, sw1, sb1, sw2, sb2, iw1, ib1, iw2, ib2,
                     uw1, ub1, uw2, ub2, dw1, db1, dw2, db2, ws);
  hipLaunchKernelGGL(rollout_kernel, dim3(2*BB), dim3(1024), smem_bytes, stream,
                     gt, rs, ew1, eb1, db2, ws, out);
}

// Round 13
// 189.390 us; speedup vs baseline: 1.0728x; 1.0635x over previous
//
#include <hip/hip_runtime.h>

// Problem constants
#define BB 128
#define TT 6
#define KK 64
#define DD 8
#define HH 128
#define NSTEP 5
#define LDP 136      // padded LDS row (u16 elems): 272B = 17*16B, 16B-aligned rows
#define PREDSZ (BB*NSTEP*KK*DD)   // 327680

typedef unsigned short u16;
typedef unsigned int   u32;
typedef _Float16 f16;
typedef __attribute__((ext_vector_type(8))) _Float16 f16x8;
typedef __attribute__((ext_vector_type(4))) float f32x4;
typedef __attribute__((ext_vector_type(2))) _Float16 h2;

union h2u { u32 u; h2 h; };
union hu  { u16 u; f16 h; };

__device__ __forceinline__ u16 f2h_bits(float f){
  hu v; v.h = (f16)f; return v.u;     // v_cvt_f16_f32, 1 instr
}
__device__ __forceinline__ u32 pk2(float x, float y){  // two cvts + pack
  hu a, b; a.h = (f16)x; b.h = (f16)y;
  return (u32)a.u | ((u32)b.u << 16);
}
__device__ __forceinline__ h2 u2h(u32 x){ h2u t; t.u = x; return t.h; }
__device__ __forceinline__ u32 h2u_(h2 x){ h2u t; t.h = x; return t.u; }

// ---------------- ws layout (u16 element offsets) ----------------
// Fused weight matrices (exact fp32 products, cast f16), wave-coalesced frags:
//   FR[g=8][kc=4][lane=64][8] : elem off = g*2048 + kc*512 + lane*8
// SUIU (K=256): FR[g=8][kc=8][lane=64][8], kc<4 = SU rows, kc>=4 = IU rows.
#define O_EWA   0        // ew2 @ wi_a
#define O_EWB   16384    // ew2 @ wi_b
#define O_EWS   32768    // ew2 @ self_w1
#define O_SUIU  49152    // [self_w2 @ uw1_top | (inter_w2 @ uw1_bot)/64]  (32768 elems)
#define O_UD    81920    // upd_w2 @ dec_w1
#define O_DET   98304    // dec_w2 @ enc_w1
#define O_DW2T  114688   // dw2 transposed f16 [8][128]
#define BIASF   57856    // float idx: bA,bB,bS,bU,bUD,deb  (6 x 128 f32)
// pair-exchange region:
#define O_XBUF  131072                    // u16: [pairslot=batch*2+half][slot=2][4096]
#define O_FLAG  (O_XBUF + 128*2*2*4096)   // u16 offset of u32 flags[256][2]

// ---- 16-row GEMM: O(16 local rows x 128) = A@W [+ bias]; wave (wn,wm) -> 16 cols, 1 m-tile ----
// A, O are 32-row local buffers; rows (wm<<4)+...
template<bool RELU>
__device__ __forceinline__ void gemm16(const u16 (*A)[LDP], const u16* __restrict__ wt,
    float bias, u16 (*O)[LDP], int wn, int wm, int l15, int q, int n, int lane)
{
  f16x8 bf[4];
#pragma unroll
  for (int kc=0; kc<4; ++kc)
    bf[kc] = *(const f16x8*)(wt + (wn<<11) + (kc<<9) + (lane<<3));
  f32x4 acc = {0.f,0.f,0.f,0.f};
#pragma unroll
  for (int kc=0; kc<4; ++kc){
    f16x8 af = *(const f16x8*)&A[(wm<<4)+l15][(kc<<5)+(q<<3)];
    acc = __builtin_amdgcn_mfma_f32_16x16x32_f16(af, bf[kc], acc, 0,0,0);
  }
#pragma unroll
  for (int e=0; e<4; ++e){
    float v = acc[e] + bias;
    if (RELU) v = fmaxf(v, 0.f);
    O[(wm<<4)+(q<<2)+e][n] = f2h_bits(v);   // C/D: col=lane&15, row=q*4+e
  }
}

// K=256: O(16 local rows) = relu([A1 | A2] @ [SU|IU] + bU); A1/A2 32-row local buffers
__device__ __forceinline__ void gemm256_16(const u16 (*A1)[LDP], const u16 (*A2)[LDP],
    const u16* __restrict__ wt, float bias, u16 (*O)[LDP], int wn, int wm, int l15, int q, int n, int lane)
{
  f16x8 bf[8];
#pragma unroll
  for (int kc=0; kc<8; ++kc)
    bf[kc] = *(const f16x8*)(wt + (wn<<12) + (kc<<9) + (lane<<3));
  f32x4 acc = {0.f,0.f,0.f,0.f};
#pragma unroll
  for (int kc=0; kc<8; ++kc){
    const u16 (*As)[LDP] = (kc<4) ? A1 : A2;
    f16x8 af = *(const f16x8*)&As[(wm<<4)+l15][((kc&3)<<5)+(q<<3)];
    acc = __builtin_amdgcn_mfma_f32_16x16x32_f16(af, bf[kc], acc, 0,0,0);
  }
#pragma unroll
  for (int e=0; e<4; ++e){
    float v = fmaxf(acc[e] + bias, 0.f);
    O[(wm<<4)+(q<<2)+e][n] = f2h_bits(v);
  }
}

// ---- Fused stage1 + interaction, 16-wave pair-split version ----
// Block (batch,half) holds FULL h (64 rows) in P. Wave (wn,wm) computes:
//   a = h@EWA for ALL 64 rows x its 16 cols (full height required by sum over i);
//   b, hs only for its own 16 rows (global rows rowbase = half*32 + wm*16);
//   interaction Ssum[j,n] = sum_i relu(a[i,n]+b[j,n]) for its own 16 j's, wave-locally.
__device__ __forceinline__ void fusedS1I(const u16 (*P)[LDP], const u16* __restrict__ ws,
    float bAv, float bBv, float bSv,
    u16 (*Q)[LDP], u16 (*S)[LDP],
    int wn, int wm, int half, int l15, int q, int n, int lane)
{
  const int rowbase = (half<<5) + (wm<<4);
  u32 aPk[4][2];   // [mt][pair]: a rows mt*16+q*4+{2p,2p+1}, col n (f16 pairs)
  {
    f16x8 fa[4];
#pragma unroll
    for (int kc=0; kc<4; ++kc)
      fa[kc] = *(const f16x8*)(ws + O_EWA + (wn<<11) + (kc<<9) + (lane<<3));
#pragma unroll
    for (int mt=0; mt<4; ++mt){
      f32x4 aA = {0.f,0.f,0.f,0.f};
#pragma unroll
      for (int kc=0; kc<4; ++kc){
        f16x8 af = *(const f16x8*)&P[(mt<<4)+l15][(kc<<5)+(q<<3)];
        aA = __builtin_amdgcn_mfma_f32_16x16x32_f16(af, fa[kc], aA, 0,0,0);
      }
      aPk[mt][0] = pk2(aA[0]+bAv, aA[1]+bAv);
      aPk[mt][1] = pk2(aA[2]+bAv, aA[3]+bAv);
    }
  }
  u32 bPk[2];
  {
    f16x8 fb[4], fs[4], af[4];
#pragma unroll
    for (int kc=0; kc<4; ++kc){
      const int o = (wn<<11) + (kc<<9) + (lane<<3);
      fb[kc] = *(const f16x8*)(ws + O_EWB + o);
      fs[kc] = *(const f16x8*)(ws + O_EWS + o);
      af[kc] = *(const f16x8*)&P[rowbase+l15][(kc<<5)+(q<<3)];
    }
    f32x4 aB = {0.f,0.f,0.f,0.f}, aS = {0.f,0.f,0.f,0.f};
#pragma unroll
    for (int kc=0; kc<4; ++kc){
      aB = __builtin_amdgcn_mfma_f32_16x16x32_f16(af[kc], fb[kc], aB, 0,0,0);
      aS = __builtin_amdgcn_mfma_f32_16x16x32_f16(af[kc], fs[kc], aS, 0,0,0);
    }
    bPk[0] = pk2(aB[0]+bBv, aB[1]+bBv);
    bPk[1] = pk2(aB[2]+bBv, aB[3]+bBv);
#pragma unroll
    for (int e=0; e<4; ++e)
      S[(wm<<4)+(q<<2)+e][n] = f2h_bits(fmaxf(aS[e]+bSv, 0.f));
  }

  // gather the 16 own b's across q-lanes
  u32 jt[4][2];
#pragma unroll
  for (int qp=0; qp<4; ++qp){
    const int src = (qp<<4) + l15;
    jt[qp][0] = (u32)__shfl((int)bPk[0], src);
    jt[qp][1] = (u32)__shfl((int)bPk[1], src);
  }
  h2 z; z.x = (f16)0.f; z.y = (f16)0.f;
  h2 s[4][2];
#pragma unroll
  for (int qp=0; qp<4; ++qp){ s[qp][0] = z; s[qp][1] = z; }
  // accumulate over this thread's 16 i-values (4 mt x 2 pairs x 2 f16)
#pragma unroll
  for (int mt=0; mt<4; ++mt)
#pragma unroll
    for (int pp=0; pp<2; ++pp){
      const u32 ap = aPk[mt][pp];
      const h2 hl = u2h(__builtin_amdgcn_perm(ap, ap, 0x01000100));  // lo f16 dup
      const h2 hh = u2h(__builtin_amdgcn_perm(ap, ap, 0x03020302));  // hi f16 dup
#pragma unroll
      for (int qp=0; qp<4; ++qp)
#pragma unroll
        for (int p=0; p<2; ++p){
          const h2 bt = u2h(jt[qp][p]);
          s[qp][p] += __builtin_elementwise_max(hl + bt, z);
          s[qp][p] += __builtin_elementwise_max(hh + bt, z);
        }
    }
  // reduce over the 4 q-threads
#pragma unroll
  for (int m=0; m<2; ++m){
    const int msk = 16 << m;
#pragma unroll
    for (int qp=0; qp<4; ++qp)
#pragma unroll
      for (int p=0; p<2; ++p)
        s[qp][p] += u2h((u32)__shfl_xor((int)h2u_(s[qp][p]), msk));
  }
  // write own q-slot: local j = wm*16 + q*4 + 2p + {0,1}
#pragma unroll
  for (int qp=0; qp<4; ++qp) if (qp == q){
#pragma unroll
    for (int p=0; p<2; ++p){
      const int j = (wm<<4) + (qp<<2) + (p<<1);
      hu lo, hi; lo.h = s[qp][p].x; hi.h = s[qp][p].y;
      Q[j][n]   = lo.u;
      Q[j+1][n] = hi.u;
    }
  }
}

// pred(own 32 rows x 8) = hd @ dw2 + db2 -> global out (side branch, tid<256)
__device__ __forceinline__ void dec_out(const u16 (*S)[LDP], const u16* __restrict__ dwt,
    float db2v, float* __restrict__ out, int batch, int half, int t, int tid)
{
  const int r = tid>>3, d = tid&7;          // r local 0..31
  float acc = db2v;
#pragma unroll
  for (int c=0; c<16; ++c){
    f16x8 hv = *(const f16x8*)&S[r][c<<3];
    f16x8 wv = *(const f16x8*)(dwt + (d<<7) + (c<<3));
#pragma unroll
    for (int j=0; j<8; ++j)
      acc += (float)hv[j] * (float)wv[j];
  }
  out[(size_t)(batch*NSTEP + t)*(KK*DD) + ((half<<5)+r)*DD + d] = acc;
}

// h0 = relu(gt0 @ ew1 + eb1), full 64 rows (1024 threads: 8 rows each)
__device__ __forceinline__ void mlp_in8(const float* pred, const float* __restrict__ W,
    const float* __restrict__ bias, u16 (*O)[LDP], int tid)
{
  const int h = tid & 127, rg = tid >> 7;    // rg in [0,8)
  float wv[DD];
#pragma unroll
  for (int d=0; d<DD; ++d) wv[d] = W[d*HH + h];
  const float bv = bias[h];
  for (int rr=0; rr<8; ++rr){
    const int r = (rg<<3) + rr;
    float v = bv;
#pragma unroll
    for (int d=0; d<DD; ++d) v += pred[r*DD + d] * wv[d];
    O[r][h] = f2h_bits(fmaxf(v, 0.f));
  }
}

// ---------------- prep: fused fp32 weight products -> f16 frags (+ flag zeroing) ----------------
// REVERTED to the proven 455-block / 1-output-per-thread mapping (bench gap 104us across
// r3-r10; the 96-block 4-wide mapping of r11/r12 cost +17us from CU starvation -- occupancy,
// not per-thread ILP, limits this kernel). One additive tweak at UNCHANGED occupancy: the
// A operand is contiguous in m, so the dot is m-unrolled by 4 with one float4 A-load + 4
// broadcast B-scalars (256 -> 160 load-instrs/thread). Accumulation order stays ascending-m
// sequential adds -> bitwise-identical outputs to the r3-r10 prep.
__global__ void prep_kernel(
    const float* __restrict__ ew1, const float* __restrict__ eb1,
    const float* __restrict__ ew2, const float* __restrict__ eb2,
    const float* __restrict__ sw1, const float* __restrict__ sb1,
    const float* __restrict__ sw2, const float* __restrict__ sb2,
    const float* __restrict__ iw1, const float* __restrict__ ib1,
    const float* __restrict__ iw2, const float* __restrict__ ib2,
    const float* __restrict__ uw1, const float* __restrict__ ub1,
    const float* __restrict__ uw2, const float* __restrict__ ub2,
    const float* __restrict__ dw1, const float* __restrict__ db1,
    const float* __restrict__ dw2, const float* __restrict__ db2,
    u16* __restrict__ ws)
{
  const int idx = blockIdx.x * 256 + threadIdx.x;
  if (idx < 512) ((u32*)(ws + O_FLAG))[idx] = 0;   // zero exchange flags each launch

  if (idx < 98304){
    // ---- heavy: one 128-long fp32 dot per thread, mapping identical to r3-r10 ----
    const float* A;        // row operand (contiguous in m)
    const float* B0;       // column operand base (row-major [*, 128])
    int nn;
    float sc = 1.f;
    if (idx < 49152){
      const int mat = idx >> 14, r = idx & 16383;
      const int g = r >> 11, kc = (r >> 9) & 3, lane = (r >> 3) & 63, e = r & 7;
      const int k  = (kc<<5) + ((lane>>4)<<3) + e;
      nn = (g<<4) + (lane & 15);
      A  = ew2 + k*HH;
      B0 = (mat==0) ? iw1 : (mat==1) ? (iw1 + HH*HH) : sw1;
    } else if (idx < 81920){
      const int r = idx - 49152;
      const int g = r >> 12, kc = (r >> 9) & 7, lane = (r >> 3) & 63, e = r & 7;
      const int k  = ((kc&3)<<5) + ((lane>>4)<<3) + e;
      nn = (g<<4) + (lane & 15);
      if (kc < 4){ A = sw2 + k*HH; B0 = uw1; }
      else       { A = iw2 + k*HH; B0 = uw1 + HH*HH; sc = 1.f/64.f; }
    } else {
      const int r = idx - 81920;
      const int g = r >> 11, kc = (r >> 9) & 3, lane = (r >> 3) & 63, e = r & 7;
      const int k  = (kc<<5) + ((lane>>4)<<3) + e;
      nn = (g<<4) + (lane & 15);
      A = uw2 + k*HH; B0 = dw1;
    }
    float v = 0.f;
#pragma unroll 2
    for (int m=0; m<HH; m+=4){
      const float4 a4 = *(const float4*)(A + m);
      v += a4.x * B0[(m+0)*HH + nn];
      v += a4.y * B0[(m+1)*HH + nn];
      v += a4.z * B0[(m+2)*HH + nn];
      v += a4.w * B0[(m+3)*HH + nn];
    }
    hu hb; hb.h = (f16)(v*sc); ws[idx] = hb.u;
  } else if (idx < 114688){
    // DET frags: DE = dw2 @ ew1  (K=8 inner)
    const int r = idx - 98304;
    const int g = r >> 11, kc = (r >> 9) & 3, lane = (r >> 3) & 63, e = r & 7;
    const int k  = (kc<<5) + ((lane>>4)<<3) + e;
    const int nn = (g<<4) + (lane & 15);
    float v = 0.f;
#pragma unroll
    for (int d=0; d<DD; ++d) v += dw2[k*DD+d] * ew1[d*HH+nn];
    hu hb; hb.h = (f16)v; ws[idx] = hb.u;
  } else if (idx < 115712){
    const int r = idx - 114688, d = r >> 7, hcol = r & 127;   // dw2T [8][128]
    hu hb; hb.h = (f16)dw2[hcol*DD + d]; ws[idx] = hb.u;
  } else if (idx < 116480){
    // fused biases (f32)
    const int j = idx - 115712, which = j >> 7, nn = j & 127;
    float v = 0.f;
    switch (which){
      case 0: for (int m=0; m<HH; ++m) v += eb2[m] * iw1[m*HH+nn]; break;                  // bA
      case 1: for (int m=0; m<HH; ++m) v += eb2[m] * iw1[(HH+m)*HH+nn]; v += ib1[nn]; break; // bB
      case 2: for (int m=0; m<HH; ++m) v += eb2[m] * sw1[m*HH+nn]; v += sb1[nn]; break;    // bS
      case 3: for (int m=0; m<HH; ++m) v += sb2[m]*uw1[m*HH+nn] + ib2[m]*uw1[(HH+m)*HH+nn];
              v += ub1[nn]; break;                                                          // bU
      case 4: for (int m=0; m<HH; ++m) v += ub2[m] * dw1[m*HH+nn]; v += db1[nn]; break;    // bUD
      default:
#pragma unroll
        for (int d=0; d<DD; ++d) v += db2[d] * ew1[d*HH+nn];
        v += eb1[nn]; break;                                                                // deb
    }
    ((float*)ws)[BIASF + j] = v;
  }
}

// ---------------- rollout: 2 blocks / batch (256 blocks, 1/CU), 1024 threads (4 waves/SIMD) ----------------
// EXACT round-7 structure -- the measured optimum of this family (80.6-82.4us rollout):
// pairwise same-XCD exchange via LDS import, block-wide tid0 acquire-spin. All attempted
// deviations regressed: 4-way exchange (r6, 200us), per-wave spin / xbuf-direct reads
// (r8/r9, 237/112us: L1-invalidate thrash + 16x read amplification), register-persistent
// B-frags (r10, 98us: compiler demoted them to scratch -- FETCH 3.9->37MB).
__global__ __launch_bounds__(1024, 1) void rollout_kernel(
    const float* __restrict__ gt, const int* __restrict__ rollout,
    const float* __restrict__ ew1, const float* __restrict__ eb1,
    const float* __restrict__ db2,
    u16* __restrict__ ws, float* __restrict__ out)
{
  extern __shared__ u16 smem[];
  u16 (*P)[LDP] = (u16(*)[LDP])smem;                 // full h: 64 rows
  u16 (*Q)[LDP] = (u16(*)[LDP])(smem + 64*LDP);      // Ssum own half: 32 rows
  u16 (*R)[LDP] = (u16(*)[LDP])(smem + 96*LDP);      // hu own half: 32 rows
  u16 (*S)[LDP] = (u16(*)[LDP])(smem + 128*LDP);     // hs/hd own half: 32 rows
  float* predbuf = (float*)Q;                        // 512 f32, init only

  const int tid = threadIdx.x, blk = blockIdx.x;
  const int batch = blk & 127, half = blk >> 7;      // partner blk^128 -> same XCD
  const int w = tid >> 6, lane = tid & 63;
  const int l15 = lane & 15, q = lane >> 4;
  const int wn = w & 7, wm = w >> 3;
  const int n = (wn << 4) + l15;

  int ns = rollout[0];
  if (ns > TT-1) ns = TT-1;
  if (ns > NSTEP) ns = NSTEP;
  if (ns < 0) ns = 0;

  // fused per-thread biases (col n)
  const float* bf32 = (const float*)ws;
  const float bAv  = bf32[BIASF + n];
  const float bBv  = bf32[BIASF + 128 + n];
  const float bSv  = bf32[BIASF + 256 + n];
  const float bUv  = bf32[BIASF + 384 + n];
  const float bUDv = bf32[BIASF + 512 + n];
  const float debv = bf32[BIASF + 640 + n];
  const float db2v = db2[tid & 7];

  // exchange bookkeeping
  u16* xbuf  = ws + O_XBUF;
  u32* flags = (u32*)(ws + O_FLAG);
  const int own  = (batch<<1) + half;
  const int prt  = (batch<<1) + (1-half);

  // init: targets copy (own half share) + h0 = relu(gt[:,0]@ew1 + eb1) (full)
  for (int i = tid; i < (NSTEP*KK*DD/2); i += 1024)
    out[PREDSZ + batch*(NSTEP*KK*DD) + half*(NSTEP*KK*DD/2) + i]
      = gt[(size_t)batch*(TT*KK*DD) + KK*DD + half*(NSTEP*KK*DD/2) + i];
  if (tid < KK*DD) predbuf[tid] = gt[(size_t)batch*(TT*KK*DD) + tid];
  __syncthreads();
  mlp_in8(predbuf, ew1, eb1, P, tid);               // P = h0 (64 rows)
  __syncthreads();

  for (int t=0; t<ns; ++t){
    fusedS1I(P, ws, bAv, bBv, bSv, Q, S, wn, wm, half, l15, q, n, lane); // Q=Ssum, S=hs (32)
    __syncthreads();
    gemm256_16(S, Q, ws+O_SUIU, bUv, R, wn, wm, l15, q, n, lane);  // R = hu (32)
    __syncthreads();
    gemm16<true>(R, ws+O_UD, bUDv, S, wn, wm, l15, q, n, lane);    // S = hd (32)
    __syncthreads();
    // DET: h_next own rows -> P (+ fused export to xbuf)
    {
      f16x8 bfw[4];
#pragma unroll
      for (int kc=0; kc<4; ++kc)
        bfw[kc] = *(const f16x8*)(ws + O_DET + (wn<<11) + (kc<<9) + (lane<<3));
      f32x4 acc = {0.f,0.f,0.f,0.f};
#pragma unroll
      for (int kc=0; kc<4; ++kc){
        f16x8 af = *(const f16x8*)&S[(wm<<4)+l15][(kc<<5)+(q<<3)];
        acc = __builtin_amdgcn_mfma_f32_16x16x32_f16(af, bfw[kc], acc, 0,0,0);
      }
      const int par = t & 1;
      u16* ob = xbuf + (((own<<1)|par)<<12);
      const bool exch = (t < ns-1);
#pragma unroll
      for (int e=0; e<4; ++e){
        const u16 bits = f2h_bits(fmaxf(acc[e]+debv, 0.f));
        const int lr = (wm<<4)+(q<<2)+e;               // local row in half (0..31)
        P[(half<<5)+lr][n] = bits;
        if (exch) ob[(lr<<7) | n] = bits;
      }
    }
    if (tid < 256) dec_out(S, ws+O_DW2T, db2v, out, batch, half, t, tid);
    __syncthreads();

    if (t < ns-1){
      const int par = t & 1;
      if (tid == 0){
        __hip_atomic_store(&flags[(own<<1)|par], (u32)(t+1),
                           __ATOMIC_RELEASE, __HIP_MEMORY_SCOPE_AGENT);
        int guard = 0;
        while (__hip_atomic_load(&flags[(prt<<1)|par],
                 __ATOMIC_ACQUIRE, __HIP_MEMORY_SCOPE_AGENT) != (u32)(t+1)
               && guard < (1<<22)){
          ++guard;
          __builtin_amdgcn_s_sleep(1);
        }
      }
      __syncthreads();
      // import partner half into P
      if (tid < 512){
        const u16* pb = xbuf + (((prt<<1)|par)<<12);
        const int r = tid >> 4, c = (tid & 15) << 3;
        *(f16x8*)&P[((1-half)<<5)+r][c] = *(const f16x8*)(pb + (r<<7) + c);
      }
      __syncthreads();
    }
  }
}

extern "C" void kernel_launch(void* const* d_in, const int* in_sizes, int n_in,
                              void* d_out, int out_size, void* d_ws, size_t ws_size,
                              hipStream_t stream)
{
  const float* gt  = (const float*)d_in[0];
  const int*   rs  = (const int*)d_in[1];
  const float* ew1 = (const float*)d_in[2];
  const float* eb1 = (const float*)d_in[3];
  const float* ew2 = (const float*)d_in[4];
  const float* eb2 = (const float*)d_in[5];
  const float* sw1 = (const float*)d_in[6];
  const float* sb1 = (const float*)d_in[7];
  const float* sw2 = (const float*)d_in[8];
  const float* sb2 = (const float*)d_in[9];
  const float* iw1 = (const float*)d_in[10];
  const float* ib1 = (const float*)d_in[11];
  const float* iw2 = (const float*)d_in[12];
  const float* ib2 = (const float*)d_in[13];
  const float* uw1 = (const float*)d_in[14];
  const float* ub1 = (const float*)d_in[15];
  const float* uw2 = (const float*)d_in[16];
  const float* ub2 = (const float*)d_in[17];
  const float* dw1 = (const float*)d_in[18];
  const float* db1 = (const float*)d_in[19];
  const float* dw2 = (const float*)d_in[20];
  const float* db2 = (const float*)d_in[21];
  float* out = (float*)d_out;
  u16*   ws  = (u16*)d_ws;

  const int smem_bytes = 160 * LDP * (int)sizeof(u16);  // 43520
  (void)hipFuncSetAttribute((const void*)rollout_kernel,
                            hipFuncAttributeMaxDynamicSharedMemorySize, smem_bytes);

  hipLaunchKernelGGL(prep_kernel, dim3(455), dim3(256), 0, stream,
                     ew1, eb1, ew2, eb2, sw1, sb1, sw2, sb2, iw1, ib1, iw2, ib2,
                     uw1, ub1, uw2, ub2, dw1, db1, dw2, db2, ws);
  hipLaunchKernelGGL(rollout_kernel, dim3(2*BB), dim3(1024), smem_bytes, stream,
                     gt, rs, ew1, eb1, db2, ws, out);
}

// Round 14
// 181.922 us; speedup vs baseline: 1.1168x; 1.0411x over previous
//
#include <hip/hip_runtime.h>

// Problem constants
#define BB 128
#define TT 6
#define KK 64
#define DD 8
#define HH 128
#define NSTEP 5
#define LDP 136      // padded LDS row (u16 elems): 272B = 17*16B, 16B-aligned rows
#define PREDSZ (BB*NSTEP*KK*DD)   // 327680

typedef unsigned short u16;
typedef unsigned int   u32;
typedef _Float16 f16;
typedef __attribute__((ext_vector_type(8))) _Float16 f16x8;
typedef __attribute__((ext_vector_type(4))) float f32x4;
typedef __attribute__((ext_vector_type(2))) _Float16 h2;

union h2u { u32 u; h2 h; };
union hu  { u16 u; f16 h; };

__device__ __forceinline__ u16 f2h_bits(float f){
  hu v; v.h = (f16)f; return v.u;     // v_cvt_f16_f32, 1 instr
}
__device__ __forceinline__ u32 pk2(float x, float y){  // two cvts + pack
  hu a, b; a.h = (f16)x; b.h = (f16)y;
  return (u32)a.u | ((u32)b.u << 16);
}
__device__ __forceinline__ h2 u2h(u32 x){ h2u t; t.u = x; return t.h; }
__device__ __forceinline__ u32 h2u_(h2 x){ h2u t; t.h = x; return t.u; }

// ---------------- ws layout (u16 element offsets) ----------------
// Fused weight matrices (exact fp32 products, cast f16), wave-coalesced frags:
//   FR[g=8][kc=4][lane=64][8] : elem off = g*2048 + kc*512 + lane*8
// SUIU (K=256): FR[g=8][kc=8][lane=64][8], kc<4 = SU rows, kc>=4 = IU rows.
#define O_EWA   0        // ew2 @ wi_a
#define O_EWB   16384    // ew2 @ wi_b
#define O_EWS   32768    // ew2 @ self_w1
#define O_SUIU  49152    // [self_w2 @ uw1_top | (inter_w2 @ uw1_bot)/64]  (32768 elems)
#define O_UD    81920    // upd_w2 @ dec_w1
#define O_DET   98304    // dec_w2 @ enc_w1
#define O_DW2T  114688   // dw2 transposed f16 [8][128]
#define BIASF   57856    // float idx: bA,bB,bS,bU,bUD,deb  (6 x 128 f32)
// pair-exchange region:
#define O_XBUF  131072                    // u16: [pairslot=batch*2+half][slot=2][4096]
#define O_FLAG  (O_XBUF + 128*2*2*4096)   // u16 offset of u32 flags[256][2]

// ---- 16-row GEMM with PRELOADED B-frags: O(16 local rows) = A@W [+ bias] ----
// Loads are issued by the caller BEFORE the preceding barrier (T14 issue-early);
// live range spans one barrier only, so no scratch demotion (unlike r10's loop-persist).
template<bool RELU>
__device__ __forceinline__ void gemm16P(const u16 (*A)[LDP], const f16x8* bf,
    float bias, u16 (*O)[LDP], int wm, int l15, int q, int n)
{
  f32x4 acc = {0.f,0.f,0.f,0.f};
#pragma unroll
  for (int kc=0; kc<4; ++kc){
    f16x8 af = *(const f16x8*)&A[(wm<<4)+l15][(kc<<5)+(q<<3)];
    acc = __builtin_amdgcn_mfma_f32_16x16x32_f16(af, bf[kc], acc, 0,0,0);
  }
#pragma unroll
  for (int e=0; e<4; ++e){
    float v = acc[e] + bias;
    if (RELU) v = fmaxf(v, 0.f);
    O[(wm<<4)+(q<<2)+e][n] = f2h_bits(v);   // C/D: col=lane&15, row=q*4+e
  }
}

// K=256 with PRELOADED B-frags: O(16 local rows) = relu([A1|A2]@[SU|IU] + bU)
__device__ __forceinline__ void gemm256P(const u16 (*A1)[LDP], const u16 (*A2)[LDP],
    const f16x8* bf /*8*/, float bias, u16 (*O)[LDP], int wm, int l15, int q, int n)
{
  f32x4 acc = {0.f,0.f,0.f,0.f};
#pragma unroll
  for (int kc=0; kc<8; ++kc){
    const u16 (*As)[LDP] = (kc<4) ? A1 : A2;
    f16x8 af = *(const f16x8*)&As[(wm<<4)+l15][((kc&3)<<5)+(q<<3)];
    acc = __builtin_amdgcn_mfma_f32_16x16x32_f16(af, bf[kc], acc, 0,0,0);
  }
#pragma unroll
  for (int e=0; e<4; ++e){
    float v = fmaxf(acc[e] + bias, 0.f);
    O[(wm<<4)+(q<<2)+e][n] = f2h_bits(v);
  }
}

// ---- Fused stage1 + interaction, 16-wave pair-split version (r7 structure) ----
// Block (batch,half) holds FULL h (64 rows) in P. Wave (wn,wm) computes:
//   a = h@EWA for ALL 64 rows x its 16 cols (full height required by sum over i);
//   b, hs only for its own 16 rows (global rows rowbase = half*32 + wm*16);
//   interaction Ssum[j,n] = sum_i relu(a[i,n]+b[j,n]) for its own 16 j's, wave-locally.
__device__ __forceinline__ void fusedS1I(const u16 (*P)[LDP], const u16* __restrict__ ws,
    float bAv, float bBv, float bSv,
    u16 (*Q)[LDP], u16 (*S)[LDP],
    int wn, int wm, int half, int l15, int q, int n, int lane)
{
  const int rowbase = (half<<5) + (wm<<4);
  u32 aPk[4][2];   // [mt][pair]: a rows mt*16+q*4+{2p,2p+1}, col n (f16 pairs)
  {
    f16x8 fa[4];
#pragma unroll
    for (int kc=0; kc<4; ++kc)
      fa[kc] = *(const f16x8*)(ws + O_EWA + (wn<<11) + (kc<<9) + (lane<<3));
#pragma unroll
    for (int mt=0; mt<4; ++mt){
      f32x4 aA = {0.f,0.f,0.f,0.f};
#pragma unroll
      for (int kc=0; kc<4; ++kc){
        f16x8 af = *(const f16x8*)&P[(mt<<4)+l15][(kc<<5)+(q<<3)];
        aA = __builtin_amdgcn_mfma_f32_16x16x32_f16(af, fa[kc], aA, 0,0,0);
      }
      aPk[mt][0] = pk2(aA[0]+bAv, aA[1]+bAv);
      aPk[mt][1] = pk2(aA[2]+bAv, aA[3]+bAv);
    }
  }
  u32 bPk[2];
  {
    f16x8 fb[4], fs[4], af[4];
#pragma unroll
    for (int kc=0; kc<4; ++kc){
      const int o = (wn<<11) + (kc<<9) + (lane<<3);
      fb[kc] = *(const f16x8*)(ws + O_EWB + o);
      fs[kc] = *(const f16x8*)(ws + O_EWS + o);
      af[kc] = *(const f16x8*)&P[rowbase+l15][(kc<<5)+(q<<3)];
    }
    f32x4 aB = {0.f,0.f,0.f,0.f}, aS = {0.f,0.f,0.f,0.f};
#pragma unroll
    for (int kc=0; kc<4; ++kc){
      aB = __builtin_amdgcn_mfma_f32_16x16x32_f16(af[kc], fb[kc], aB, 0,0,0);
      aS = __builtin_amdgcn_mfma_f32_16x16x32_f16(af[kc], fs[kc], aS, 0,0,0);
    }
    bPk[0] = pk2(aB[0]+bBv, aB[1]+bBv);
    bPk[1] = pk2(aB[2]+bBv, aB[3]+bBv);
#pragma unroll
    for (int e=0; e<4; ++e)
      S[(wm<<4)+(q<<2)+e][n] = f2h_bits(fmaxf(aS[e]+bSv, 0.f));
  }

  // gather the 16 own b's across q-lanes
  u32 jt[4][2];
#pragma unroll
  for (int qp=0; qp<4; ++qp){
    const int src = (qp<<4) + l15;
    jt[qp][0] = (u32)__shfl((int)bPk[0], src);
    jt[qp][1] = (u32)__shfl((int)bPk[1], src);
  }
  h2 z; z.x = (f16)0.f; z.y = (f16)0.f;
  h2 s[4][2];
#pragma unroll
  for (int qp=0; qp<4; ++qp){ s[qp][0] = z; s[qp][1] = z; }
  // accumulate over this thread's 16 i-values (4 mt x 2 pairs x 2 f16)
#pragma unroll
  for (int mt=0; mt<4; ++mt)
#pragma unroll
    for (int pp=0; pp<2; ++pp){
      const u32 ap = aPk[mt][pp];
      const h2 hl = u2h(__builtin_amdgcn_perm(ap, ap, 0x01000100));  // lo f16 dup
      const h2 hh = u2h(__builtin_amdgcn_perm(ap, ap, 0x03020302));  // hi f16 dup
#pragma unroll
      for (int qp=0; qp<4; ++qp)
#pragma unroll
        for (int p=0; p<2; ++p){
          const h2 bt = u2h(jt[qp][p]);
          s[qp][p] += __builtin_elementwise_max(hl + bt, z);
          s[qp][p] += __builtin_elementwise_max(hh + bt, z);
        }
    }
  // reduce over the 4 q-threads
#pragma unroll
  for (int m=0; m<2; ++m){
    const int msk = 16 << m;
#pragma unroll
    for (int qp=0; qp<4; ++qp)
#pragma unroll
      for (int p=0; p<2; ++p)
        s[qp][p] += u2h((u32)__shfl_xor((int)h2u_(s[qp][p]), msk));
  }
  // write own q-slot: local j = wm*16 + q*4 + 2p + {0,1}
#pragma unroll
  for (int qp=0; qp<4; ++qp) if (qp == q){
#pragma unroll
    for (int p=0; p<2; ++p){
      const int j = (wm<<4) + (qp<<2) + (p<<1);
      hu lo, hi; lo.h = s[qp][p].x; hi.h = s[qp][p].y;
      Q[j][n]   = lo.u;
      Q[j+1][n] = hi.u;
    }
  }
}

// pred(own 32 rows x 8) = hd @ dw2 + db2 -> global out (side branch, tid<256)
__device__ __forceinline__ void dec_out(const u16 (*S)[LDP], const u16* __restrict__ dwt,
    float db2v, float* __restrict__ out, int batch, int half, int t, int tid)
{
  const int r = tid>>3, d = tid&7;          // r local 0..31
  float acc = db2v;
#pragma unroll
  for (int c=0; c<16; ++c){
    f16x8 hv = *(const f16x8*)&S[r][c<<3];
    f16x8 wv = *(const f16x8*)(dwt + (d<<7) + (c<<3));
#pragma unroll
    for (int j=0; j<8; ++j)
      acc += (float)hv[j] * (float)wv[j];
  }
  out[(size_t)(batch*NSTEP + t)*(KK*DD) + ((half<<5)+r)*DD + d] = acc;
}

// h0 = relu(gt0 @ ew1 + eb1), full 64 rows (1024 threads: 8 rows each)
__device__ __forceinline__ void mlp_in8(const float* pred, const float* __restrict__ W,
    const float* __restrict__ bias, u16 (*O)[LDP], int tid)
{
  const int h = tid & 127, rg = tid >> 7;    // rg in [0,8)
  float wv[DD];
#pragma unroll
  for (int d=0; d<DD; ++d) wv[d] = W[d*HH + h];
  const float bv = bias[h];
  for (int rr=0; rr<8; ++rr){
    const int r = (rg<<3) + rr;
    float v = bv;
#pragma unroll
    for (int d=0; d<DD; ++d) v += pred[r*DD + d] * wv[d];
    O[r][h] = f2h_bits(fmaxf(v, 0.f));
  }
}

// ---------------- prep: fused fp32 weight products -> f16 frags (+ flag zeroing) ----------------
// r13 version (proven): 455-block / 1-output-per-thread mapping with float4 A-loads.
__global__ void prep_kernel(
    const float* __restrict__ ew1, const float* __restrict__ eb1,
    const float* __restrict__ ew2, const float* __restrict__ eb2,
    const float* __restrict__ sw1, const float* __restrict__ sb1,
    const float* __restrict__ sw2, const float* __restrict__ sb2,
    const float* __restrict__ iw1, const float* __restrict__ ib1,
    const float* __restrict__ iw2, const float* __restrict__ ib2,
    const float* __restrict__ uw1, const float* __restrict__ ub1,
    const float* __restrict__ uw2, const float* __restrict__ ub2,
    const float* __restrict__ dw1, const float* __restrict__ db1,
    const float* __restrict__ dw2, const float* __restrict__ db2,
    u16* __restrict__ ws)
{
  const int idx = blockIdx.x * 256 + threadIdx.x;
  if (idx < 512) ((u32*)(ws + O_FLAG))[idx] = 0;   // zero exchange flags each launch

  if (idx < 98304){
    // ---- heavy: one 128-long fp32 dot per thread, mapping identical to r3-r10 ----
    const float* A;        // row operand (contiguous in m)
    const float* B0;       // column operand base (row-major [*, 128])
    int nn;
    float sc = 1.f;
    if (idx < 49152){
      const int mat = idx >> 14, r = idx & 16383;
      const int g = r >> 11, kc = (r >> 9) & 3, lane = (r >> 3) & 63, e = r & 7;
      const int k  = (kc<<5) + ((lane>>4)<<3) + e;
      nn = (g<<4) + (lane & 15);
      A  = ew2 + k*HH;
      B0 = (mat==0) ? iw1 : (mat==1) ? (iw1 + HH*HH) : sw1;
    } else if (idx < 81920){
      const int r = idx - 49152;
      const int g = r >> 12, kc = (r >> 9) & 7, lane = (r >> 3) & 63, e = r & 7;
      const int k  = ((kc&3)<<5) + ((lane>>4)<<3) + e;
      nn = (g<<4) + (lane & 15);
      if (kc < 4){ A = sw2 + k*HH; B0 = uw1; }
      else       { A = iw2 + k*HH; B0 = uw1 + HH*HH; sc = 1.f/64.f; }
    } else {
      const int r = idx - 81920;
      const int g = r >> 11, kc = (r >> 9) & 3, lane = (r >> 3) & 63, e = r & 7;
      const int k  = (kc<<5) + ((lane>>4)<<3) + e;
      nn = (g<<4) + (lane & 15);
      A = uw2 + k*HH; B0 = dw1;
    }
    float v = 0.f;
#pragma unroll 2
    for (int m=0; m<HH; m+=4){
      const float4 a4 = *(const float4*)(A + m);
      v += a4.x * B0[(m+0)*HH + nn];
      v += a4.y * B0[(m+1)*HH + nn];
      v += a4.z * B0[(m+2)*HH + nn];
      v += a4.w * B0[(m+3)*HH + nn];
    }
    hu hb; hb.h = (f16)(v*sc); ws[idx] = hb.u;
  } else if (idx < 114688){
    // DET frags: DE = dw2 @ ew1  (K=8 inner)
    const int r = idx - 98304;
    const int g = r >> 11, kc = (r >> 9) & 3, lane = (r >> 3) & 63, e = r & 7;
    const int k  = (kc<<5) + ((lane>>4)<<3) + e;
    const int nn = (g<<4) + (lane & 15);
    float v = 0.f;
#pragma unroll
    for (int d=0; d<DD; ++d) v += dw2[k*DD+d] * ew1[d*HH+nn];
    hu hb; hb.h = (f16)v; ws[idx] = hb.u;
  } else if (idx < 115712){
    const int r = idx - 114688, d = r >> 7, hcol = r & 127;   // dw2T [8][128]
    hu hb; hb.h = (f16)dw2[hcol*DD + d]; ws[idx] = hb.u;
  } else if (idx < 116480){
    // fused biases (f32)
    const int j = idx - 115712, which = j >> 7, nn = j & 127;
    float v = 0.f;
    switch (which){
      case 0: for (int m=0; m<HH; ++m) v += eb2[m] * iw1[m*HH+nn]; break;                  // bA
      case 1: for (int m=0; m<HH; ++m) v += eb2[m] * iw1[(HH+m)*HH+nn]; v += ib1[nn]; break; // bB
      case 2: for (int m=0; m<HH; ++m) v += eb2[m] * sw1[m*HH+nn]; v += sb1[nn]; break;    // bS
      case 3: for (int m=0; m<HH; ++m) v += sb2[m]*uw1[m*HH+nn] + ib2[m]*uw1[(HH+m)*HH+nn];
              v += ub1[nn]; break;                                                          // bU
      case 4: for (int m=0; m<HH; ++m) v += ub2[m] * dw1[m*HH+nn]; v += db1[nn]; break;    // bUD
      default:
#pragma unroll
        for (int d=0; d<DD; ++d) v += db2[d] * ew1[d*HH+nn];
        v += eb1[nn]; break;                                                                // deb
    }
    ((float*)ws)[BIASF + j] = v;
  }
}

// ---------------- rollout: 2 blocks / batch (256 blocks, 1/CU), 1024 threads (4 waves/SIMD) ----------------
// r7 structure (measured optimum, 80-82us) + T14 issue-early weight prefetch: the SUIU/UD/DET
// B-frag loads (loop-invariant addresses, L2-hot at ~200-400cy since the per-CU weight set
// exceeds the 32KB L1) are issued BEFORE the barrier preceding their use, hiding the load
// latency under the barrier drain. Live range spans ONE barrier (+<=32 VGPR transiently) --
// unlike r10's loop-persistent frags, no scratch demotion expected. All math, LDS layout,
// and the pairwise exchange protocol are byte-identical to r13.
__global__ __launch_bounds__(1024, 1) void rollout_kernel(
    const float* __restrict__ gt, const int* __restrict__ rollout,
    const float* __restrict__ ew1, const float* __restrict__ eb1,
    const float* __restrict__ db2,
    u16* __restrict__ ws, float* __restrict__ out)
{
  extern __shared__ u16 smem[];
  u16 (*P)[LDP] = (u16(*)[LDP])smem;                 // full h: 64 rows
  u16 (*Q)[LDP] = (u16(*)[LDP])(smem + 64*LDP);      // Ssum own half: 32 rows
  u16 (*R)[LDP] = (u16(*)[LDP])(smem + 96*LDP);      // hu own half: 32 rows
  u16 (*S)[LDP] = (u16(*)[LDP])(smem + 128*LDP);     // hs/hd own half: 32 rows
  float* predbuf = (float*)Q;                        // 512 f32, init only

  const int tid = threadIdx.x, blk = blockIdx.x;
  const int batch = blk & 127, half = blk >> 7;      // partner blk^128 -> same XCD
  const int w = tid >> 6, lane = tid & 63;
  const int l15 = lane & 15, q = lane >> 4;
  const int wn = w & 7, wm = w >> 3;
  const int n = (wn << 4) + l15;

  int ns = rollout[0];
  if (ns > TT-1) ns = TT-1;
  if (ns > NSTEP) ns = NSTEP;
  if (ns < 0) ns = 0;

  // fused per-thread biases (col n)
  const float* bf32 = (const float*)ws;
  const float bAv  = bf32[BIASF + n];
  const float bBv  = bf32[BIASF + 128 + n];
  const float bSv  = bf32[BIASF + 256 + n];
  const float bUv  = bf32[BIASF + 384 + n];
  const float bUDv = bf32[BIASF + 512 + n];
  const float debv = bf32[BIASF + 640 + n];
  const float db2v = db2[tid & 7];

  // exchange bookkeeping
  u16* xbuf  = ws + O_XBUF;
  u32* flags = (u32*)(ws + O_FLAG);
  const int own  = (batch<<1) + half;
  const int prt  = (batch<<1) + (1-half);

  // init: targets copy (own half share) + h0 = relu(gt[:,0]@ew1 + eb1) (full)
  for (int i = tid; i < (NSTEP*KK*DD/2); i += 1024)
    out[PREDSZ + batch*(NSTEP*KK*DD) + half*(NSTEP*KK*DD/2) + i]
      = gt[(size_t)batch*(TT*KK*DD) + KK*DD + half*(NSTEP*KK*DD/2) + i];
  if (tid < KK*DD) predbuf[tid] = gt[(size_t)batch*(TT*KK*DD) + tid];
  __syncthreads();
  mlp_in8(predbuf, ew1, eb1, P, tid);               // P = h0 (64 rows)
  __syncthreads();

  for (int t=0; t<ns; ++t){
    fusedS1I(P, ws, bAv, bBv, bSv, Q, S, wn, wm, half, l15, q, n, lane); // Q=Ssum, S=hs (32)
    // T14: issue SUIU frag loads before the barrier (used right after it)
    f16x8 bfU[8];
#pragma unroll
    for (int kc=0; kc<8; ++kc)
      bfU[kc] = *(const f16x8*)(ws + O_SUIU + (wn<<12) + (kc<<9) + (lane<<3));
    __syncthreads();
    gemm256P(S, Q, bfU, bUv, R, wm, l15, q, n);     // R = hu (32)
    // T14: issue UD frag loads before the barrier
    f16x8 bfD[4];
#pragma unroll
    for (int kc=0; kc<4; ++kc)
      bfD[kc] = *(const f16x8*)(ws + O_UD + (wn<<11) + (kc<<9) + (lane<<3));
    __syncthreads();
    gemm16P<true>(R, bfD, bUDv, S, wm, l15, q, n);  // S = hd (32)
    // T14: issue DET frag loads before the barrier
    f16x8 bfE[4];
#pragma unroll
    for (int kc=0; kc<4; ++kc)
      bfE[kc] = *(const f16x8*)(ws + O_DET + (wn<<11) + (kc<<9) + (lane<<3));
    __syncthreads();
    // DET: h_next own rows -> P (+ fused export to xbuf)
    {
      f32x4 acc = {0.f,0.f,0.f,0.f};
#pragma unroll
      for (int kc=0; kc<4; ++kc){
        f16x8 af = *(const f16x8*)&S[(wm<<4)+l15][(kc<<5)+(q<<3)];
        acc = __builtin_amdgcn_mfma_f32_16x16x32_f16(af, bfE[kc], acc, 0,0,0);
      }
      const int par = t & 1;
      u16* ob = xbuf + (((own<<1)|par)<<12);
      const bool exch = (t < ns-1);
#pragma unroll
      for (int e=0; e<4; ++e){
        const u16 bits = f2h_bits(fmaxf(acc[e]+debv, 0.f));
        const int lr = (wm<<4)+(q<<2)+e;               // local row in half (0..31)
        P[(half<<5)+lr][n] = bits;
        if (exch) ob[(lr<<7) | n] = bits;
      }
    }
    if (tid < 256) dec_out(S, ws+O_DW2T, db2v, out, batch, half, t, tid);
    __syncthreads();

    if (t < ns-1){
      const int par = t & 1;
      if (tid == 0){
        __hip_atomic_store(&flags[(own<<1)|par], (u32)(t+1),
                           __ATOMIC_RELEASE, __HIP_MEMORY_SCOPE_AGENT);
        int guard = 0;
        while (__hip_atomic_load(&flags[(prt<<1)|par],
                 __ATOMIC_ACQUIRE, __HIP_MEMORY_SCOPE_AGENT) != (u32)(t+1)
               && guard < (1<<22)){
          ++guard;
          __builtin_amdgcn_s_sleep(1);
        }
      }
      __syncthreads();
      // import partner half into P
      if (tid < 512){
        const u16* pb = xbuf + (((prt<<1)|par)<<12);
        const int r = tid >> 4, c = (tid & 15) << 3;
        *(f16x8*)&P[((1-half)<<5)+r][c] = *(const f16x8*)(pb + (r<<7) + c);
      }
      __syncthreads();
    }
  }
}

extern "C" void kernel_launch(void* const* d_in, const int* in_sizes, int n_in,
                              void* d_out, int out_size, void* d_ws, size_t ws_size,
                              hipStream_t stream)
{
  const float* gt  = (const float*)d_in[0];
  const int*   rs  = (const int*)d_in[1];
  const float* ew1 = (const float*)d_in[2];
  const float* eb1 = (const float*)d_in[3];
  const float* ew2 = (const float*)d_in[4];
  const float* eb2 = (const float*)d_in[5];
  const float* sw1 = (const float*)d_in[6];
  const float* sb1 = (const float*)d_in[7];
  const float* sw2 = (const float*)d_in[8];
  const float* sb2 = (const float*)d_in[9];
  const float* iw1 = (const float*)d_in[10];
  const float* ib1 = (const float*)d_in[11];
  const float* iw2 = (const float*)d_in[12];
  const float* ib2 = (const float*)d_in[13];
  const float* uw1 = (const float*)d_in[14];
  const float* ub1 = (const float*)d_in[15];
  const float* uw2 = (const float*)d_in[16];
  const float* ub2 = (const float*)d_in[17];
  const float* dw1 = (const float*)d_in[18];
  const float* db1 = (const float*)d_in[19];
  const float* dw2 = (const float*)d_in[20];
  const float* db2 = (const float*)d_in[21];
  float* out = (float*)d_out;
  u16*   ws  = (u16*)d_ws;

  const int smem_bytes = 160 * LDP * (int)sizeof(u16);  // 43520
  (void)hipFuncSetAttribute((const void*)rollout_kernel,
                            hipFuncAttributeMaxDynamicSharedMemorySize, smem_bytes);

  hipLaunchKernelGGL(prep_kernel, dim3(455), dim3(256), 0, stream,
                     ew1, eb1, ew2, eb2, sw1, sb1, sw2, sb2, iw1, ib1, iw2, ib2,
                     uw1, ub1, uw2, ub2, dw1, db1, dw2, db2, ws);
  hipLaunchKernelGGL(rollout_kernel, dim3(2*BB), dim3(1024), smem_bytes, stream,
                     gt, rs, ew1, eb1, db2, ws, out);
}